// Round 1
// baseline (543.915 us; speedup 1.0000x reference)
//
#include <hip/hip_runtime.h>
#include <stdint.h>

// Problem constants (fixed by the reference)
#define NQ 1024
#define NS 131072
#define DMM 2048
#define DCC 64
#define K_TOP 16
#define EPS_RES_F 1e-8f
#define EPS_SQRT_F 1e-12f

// Tiling
#define QT 128                 // queries per block tile (main)
#define NT 64                  // stored rows per LDS tile
#define NCHUNK 64              // chunks over N
#define CHUNK (NS / NCHUNK)    // 2048
#define TILES (CHUNK / NT)     // 32
#define CAP_DEFAULT 3072       // candidate capacity per query

__device__ __forceinline__ bool lex_lt(float ka, int ia, float kb, int ib) {
  return (ka < kb) || (ka == kb && ia < ib);
}

// ---------------------------------------------------------------- G = M M^T
__global__ __launch_bounds__(256) void g_kernel(const float* __restrict__ M,
                                                float* __restrict__ G) {
  __shared__ __align__(16) float Ml[64 * 66];
  const int t = threadIdx.x;
  for (int p = 0; p < 16; ++p) {
    int i = p * 256 + t;
    Ml[(i >> 6) * 66 + (i & 63)] = M[i];
  }
  __syncthreads();
  const int e = blockIdx.x * 256 + t;  // 16 blocks x 256 = 4096 outputs
  const int i = e >> 6, j = e & 63;
  float a = 0.f;
#pragma unroll
  for (int k = 0; k < 64; ++k) a = fmaf(Ml[i * 66 + k], Ml[j * 66 + k], a);
  G[e] = a;
}

// ------------------------------------------- qc = q W ; qG = qc G ; q2 = qc.qG
// writes qGT [64][NQ] (transposed, for main) and qGr [NQ][64] (for tau)
__global__ __launch_bounds__(256) void q_kernel(
    const float* __restrict__ query, const float* __restrict__ W,
    const float* __restrict__ G, float* __restrict__ qGT,
    float* __restrict__ qGr, float* __restrict__ q2o) {
  __shared__ __align__(16) float qs[4][DMM];   // 32 KB
  __shared__ float part[4][4][64];             // 4 KB
  __shared__ float qc[4][64];
  const int t = threadIdx.x;
  const int qb = blockIdx.x * 4;  // 256 blocks x 4 queries
  {
    const float4* src = reinterpret_cast<const float4*>(query + (size_t)qb * DMM);
    float4* dst = reinterpret_cast<float4*>(&qs[0][0]);
#pragma unroll
    for (int r = 0; r < 8; ++r) dst[r * 256 + t] = src[r * 256 + t];
  }
  __syncthreads();
  const int c = t & 63, seg = t >> 6;
  float p0 = 0.f, p1 = 0.f, p2 = 0.f, p3 = 0.f;
  const int kbase = seg * 512;
  for (int ki = 0; ki < 512; ++ki) {
    const int k = kbase + ki;
    const float w = W[(size_t)k * 64 + c];
    p0 = fmaf(qs[0][k], w, p0);
    p1 = fmaf(qs[1][k], w, p1);
    p2 = fmaf(qs[2][k], w, p2);
    p3 = fmaf(qs[3][k], w, p3);
  }
  part[0][seg][c] = p0; part[1][seg][c] = p1;
  part[2][seg][c] = p2; part[3][seg][c] = p3;
  __syncthreads();
  {
    const int q = t >> 6, cc = t & 63;
    qc[q][cc] = part[q][0][cc] + part[q][1][cc] + part[q][2][cc] + part[q][3][cc];
  }
  __syncthreads();
  const int w = t >> 6, lane = t & 63;
  float g = 0.f;
  for (int j = 0; j < 64; ++j) g = fmaf(qc[w][j], G[j * 64 + lane], g);
  const int q = qb + w;
  qGT[(size_t)lane * NQ + q] = g;
  qGr[(size_t)q * DCC + lane] = g;
  float pr = qc[w][lane] * g;
#pragma unroll
  for (int off = 32; off; off >>= 1) pr += __shfl_xor(pr, off);
  if (lane == 0) q2o[q] = pr;
}

// -------------------------------------------- s2[n] = s^T G s ; ir2 = inv^2
__global__ __launch_bounds__(256) void s_kernel(
    const float* __restrict__ stored, const float* __restrict__ resil,
    const float* __restrict__ G, float* __restrict__ s2o,
    float* __restrict__ ir2o) {
  __shared__ __align__(16) float Gl[64 * 66];
  __shared__ __align__(16) float sst[NT * 64];
  __shared__ float part2[64 * 33];
  const int t = threadIdx.x;
  const int nb = blockIdx.x * NT;  // 2048 blocks
  for (int p = 0; p < 16; ++p) {
    int i = p * 256 + t;
    Gl[(i >> 6) * 66 + (i & 63)] = G[i];
  }
  {
    const float4* src = reinterpret_cast<const float4*>(stored + (size_t)nb * DCC);
    float4* dst = reinterpret_cast<float4*>(sst);
#pragma unroll
    for (int r = 0; r < 4; ++r) dst[r * 256 + t] = src[r * 256 + t];
  }
  __syncthreads();
  const int l = t & 31, tw = t >> 5;  // j0 = 2*l, n0 = 8*tw
  float acc0[8], acc1[8];
#pragma unroll
  for (int i = 0; i < 8; ++i) { acc0[i] = 0.f; acc1[i] = 0.f; }
  for (int kb = 0; kb < 16; ++kb) {
    const float2 ga0 = *reinterpret_cast<const float2*>(&Gl[(4 * kb + 0) * 66 + 2 * l]);
    const float2 ga1 = *reinterpret_cast<const float2*>(&Gl[(4 * kb + 1) * 66 + 2 * l]);
    const float2 ga2 = *reinterpret_cast<const float2*>(&Gl[(4 * kb + 2) * 66 + 2 * l]);
    const float2 ga3 = *reinterpret_cast<const float2*>(&Gl[(4 * kb + 3) * 66 + 2 * l]);
#pragma unroll
    for (int i = 0; i < 8; ++i) {
      const float4 sv = *reinterpret_cast<const float4*>(&sst[(8 * tw + i) * 64 + 4 * kb]);
      acc0[i] = fmaf(ga3.x, sv.w, fmaf(ga2.x, sv.z, fmaf(ga1.x, sv.y, fmaf(ga0.x, sv.x, acc0[i]))));
      acc1[i] = fmaf(ga3.y, sv.w, fmaf(ga2.y, sv.z, fmaf(ga1.y, sv.y, fmaf(ga0.y, sv.x, acc1[i]))));
    }
  }
#pragma unroll
  for (int i = 0; i < 8; ++i) {
    const int n = 8 * tw + i;
    const float2 sj = *reinterpret_cast<const float2*>(&sst[n * 64 + 2 * l]);
    part2[n * 33 + l] = acc0[i] * sj.x + acc1[i] * sj.y;
  }
  __syncthreads();
  if (t < 64) {
    float s = 0.f;
#pragma unroll
    for (int u = 0; u < 32; ++u) s += part2[t * 33 + u];
    s2o[nb + t] = s;
  } else if (t < 128) {
    const int n = t - 64;
    const float inv = 1.0f / (resil[nb + n] + EPS_RES_F);
    ir2o[nb + n] = inv * inv;
  }
}

// ---------------- per-query threshold: 16th smallest key over 1/64 subsample
__global__ __launch_bounds__(64) void tau_kernel(
    const float* __restrict__ stored, const float* __restrict__ qGr,
    const float* __restrict__ q2g, const float* __restrict__ s2g,
    const float* __restrict__ ir2g, float* __restrict__ tau) {
  __shared__ __align__(16) float qgl[64];
  __shared__ float kbuf[64 * 33];
  const int lane = threadIdx.x;
  const int q = blockIdx.x;
  qgl[lane] = qGr[(size_t)q * DCC + lane];
  __syncthreads();
  const float q2v = q2g[q];
  float lmin = 3.0e38f;
  int lslot = 0;
  for (int i = 0; i < 32; ++i) {
    const int n = i * 4096 + lane * 64;  // every 64th row
    const float4* srow = reinterpret_cast<const float4*>(stored + (size_t)n * DCC);
    float a = 0.f;
#pragma unroll
    for (int kb = 0; kb < 16; ++kb) {
      const float4 sv = srow[kb];
      const float4 qv = *reinterpret_cast<const float4*>(&qgl[4 * kb]);
      // NOTE: fma chain order identical to main_kernel -> bit-identical keys
      a = fmaf(qv.w, sv.w, fmaf(qv.z, sv.z, fmaf(qv.y, sv.y, fmaf(qv.x, sv.x, a))));
    }
    const float d2 = fmaf(-2.f, a, q2v + s2g[n]);
    const float key = (fmaxf(d2, 0.f) + EPS_SQRT_F) * ir2g[n];
    kbuf[lane * 33 + i] = key;
    if (key < lmin) { lmin = key; lslot = i; }
  }
  float tau16 = 0.f;
  for (int r = 0; r < 16; ++r) {
    float v = lmin;
    int who = lane;
#pragma unroll
    for (int off = 32; off; off >>= 1) {
      const float ov = __shfl_xor(v, off);
      const int ow = __shfl_xor(who, off);
      if (ov < v || (ov == v && ow < who)) { v = ov; who = ow; }
    }
    tau16 = v;
    if (lane == who) {
      kbuf[lane * 33 + lslot] = 3.0e38f;
      lmin = 3.0e38f; lslot = 0;
      for (int s = 0; s < 32; ++s) {
        const float vv = kbuf[lane * 33 + s];
        if (vv < lmin) { lmin = vv; lslot = s; }
      }
    }
  }
  if (lane == 0) tau[q] = tau16 * 1.0001f;  // margin (belt & suspenders)
}

// ------------------------- main fused pass: cross-GEMM + key + filter-append
__global__ __launch_bounds__(256, 3) void main_kernel(
    const float* __restrict__ stored, const float* __restrict__ qGT,
    const float* __restrict__ q2g, const float* __restrict__ s2g,
    const float* __restrict__ ir2g, const float* __restrict__ tau,
    int* __restrict__ cnt, float2* __restrict__ cand, int cap) {
  __shared__ __align__(16) float qg[64 * QT];  // [k][q] 32 KB
  __shared__ __align__(16) float sst[NT * 64]; // [n][k] 16 KB
  __shared__ float s2t[NT];
  __shared__ float ir2t[NT];
  const int t = threadIdx.x;
  const int chunk = blockIdx.x;   // 0..63  (XCD-pinned: linear id % 8 == chunk % 8)
  const int qtile = blockIdx.y;   // 0..7
  const int qbase = qtile * QT;
  const int nchunkbase = chunk * CHUNK;

  for (int p = 0; p < 32; ++p) {
    const int i = p * 256 + t;
    const int k = i >> 7, qq = i & 127;
    qg[k * QT + qq] = qGT[(size_t)k * NQ + qbase + qq];
  }
  const int l = t & 31, tw = t >> 5;
  const int q0 = 4 * l;
  float q2r[4], taur[4];
#pragma unroll
  for (int qq = 0; qq < 4; ++qq) {
    q2r[qq] = q2g[qbase + q0 + qq];
    taur[qq] = tau[qbase + q0 + qq];
  }

  for (int tile = 0; tile < TILES; ++tile) {
    const int nb = nchunkbase + tile * NT;
    __syncthreads();  // prev tile fully consumed before restage
    {
      const float4* src = reinterpret_cast<const float4*>(stored + (size_t)nb * DCC);
      float4* dst = reinterpret_cast<float4*>(sst);
#pragma unroll
      for (int r = 0; r < 4; ++r) dst[r * 256 + t] = src[r * 256 + t];
    }
    if (t < NT) s2t[t] = s2g[nb + t];
    else if (t < 2 * NT) ir2t[t - NT] = ir2g[nb + t - NT];
    __syncthreads();

    float acc[4][8];
#pragma unroll
    for (int qq = 0; qq < 4; ++qq)
#pragma unroll
      for (int i = 0; i < 8; ++i) acc[qq][i] = 0.f;

    for (int kb = 0; kb < 16; ++kb) {
      const float4 qa0 = *reinterpret_cast<const float4*>(&qg[(4 * kb + 0) * QT + q0]);
      const float4 qa1 = *reinterpret_cast<const float4*>(&qg[(4 * kb + 1) * QT + q0]);
      const float4 qa2 = *reinterpret_cast<const float4*>(&qg[(4 * kb + 2) * QT + q0]);
      const float4 qa3 = *reinterpret_cast<const float4*>(&qg[(4 * kb + 3) * QT + q0]);
#pragma unroll
      for (int i = 0; i < 8; ++i) {
        const float4 sv = *reinterpret_cast<const float4*>(&sst[(8 * tw + i) * 64 + 4 * kb]);
        acc[0][i] = fmaf(qa3.x, sv.w, fmaf(qa2.x, sv.z, fmaf(qa1.x, sv.y, fmaf(qa0.x, sv.x, acc[0][i]))));
        acc[1][i] = fmaf(qa3.y, sv.w, fmaf(qa2.y, sv.z, fmaf(qa1.y, sv.y, fmaf(qa0.y, sv.x, acc[1][i]))));
        acc[2][i] = fmaf(qa3.z, sv.w, fmaf(qa2.z, sv.z, fmaf(qa1.z, sv.y, fmaf(qa0.z, sv.x, acc[2][i]))));
        acc[3][i] = fmaf(qa3.w, sv.w, fmaf(qa2.w, sv.z, fmaf(qa1.w, sv.y, fmaf(qa0.w, sv.x, acc[3][i]))));
      }
    }

#pragma unroll
    for (int i = 0; i < 8; ++i) {
      const int nl = 8 * tw + i;
      const float s2v = s2t[nl];
      const float ir2v = ir2t[nl];
#pragma unroll
      for (int qq = 0; qq < 4; ++qq) {
        const float d2 = fmaf(-2.f, acc[qq][i], q2r[qq] + s2v);
        const float key = (fmaxf(d2, 0.f) + EPS_SQRT_F) * ir2v;
        if (key <= taur[qq]) {
          const int q = qbase + q0 + qq;
          const int pos = atomicAdd(&cnt[q], 1);
          if (pos < cap)
            cand[(size_t)q * cap + pos] = make_float2(key, __int_as_float(nb + nl));
        }
      }
    }
  }
}

// -------------------- exact top-16 per query from candidates, lex (key, idx)
__global__ __launch_bounds__(64) void final_kernel(
    const float2* __restrict__ cand, const int* __restrict__ cnt,
    float* __restrict__ out, int cap) {
  __shared__ float lk[64 * 17];
  __shared__ int li[64 * 17];
  const int lane = threadIdx.x;
  const int q = blockIdx.x;
  int c = cnt[q];
  if (c > cap) c = cap;
  float k16[16];
  int i16[16];
#pragma unroll
  for (int s = 0; s < 16; ++s) { k16[s] = 3.0e38f; i16[s] = 0x7FFFFFFF; }
  for (int base = lane; base < c; base += 64) {
    const float2 kv = cand[(size_t)q * cap + base];
    const float key = kv.x;
    const int idx = __float_as_int(kv.y);
    if (lex_lt(key, idx, k16[15], i16[15])) {
#pragma unroll
      for (int s = 15; s >= 1; --s) {
        const bool dprev = lex_lt(key, idx, k16[s - 1], i16[s - 1]);
        const bool dcur = lex_lt(key, idx, k16[s], i16[s]);
        const float nk = dprev ? k16[s - 1] : key;
        const int ni = dprev ? i16[s - 1] : idx;
        if (dcur) { k16[s] = nk; i16[s] = ni; }
      }
      if (lex_lt(key, idx, k16[0], i16[0])) { k16[0] = key; i16[0] = idx; }
    }
  }
#pragma unroll
  for (int s = 0; s < 16; ++s) {
    lk[lane * 17 + s] = k16[s];
    li[lane * 17 + s] = i16[s];
  }
  __syncthreads();
  int ptr = 0;
  for (int r = 0; r < K_TOP; ++r) {
    float v = lk[lane * 17 + ptr];
    int id = li[lane * 17 + ptr];
    int who = lane;
#pragma unroll
    for (int off = 32; off; off >>= 1) {
      const float ov = __shfl_xor(v, off);
      const int oid = __shfl_xor(id, off);
      const int ow = __shfl_xor(who, off);
      if (ov < v || (ov == v && oid < id)) { v = ov; id = oid; who = ow; }
    }
    if (lane == 0) {
      out[q * K_TOP + r] = sqrtf(v);                       // values
      out[NQ * K_TOP + q * K_TOP + r] = (float)id;         // indices as float
    }
    if (lane == who) ptr++;
  }
}

// ----------------------------------------------------------------- launcher
extern "C" void kernel_launch(void* const* d_in, const int* in_sizes, int n_in,
                              void* d_out, int out_size, void* d_ws, size_t ws_size,
                              hipStream_t stream) {
  const float* query  = (const float*)d_in[0];
  const float* stored = (const float*)d_in[1];
  const float* resil  = (const float*)d_in[2];
  const float* W      = (const float*)d_in[3];
  const float* M      = (const float*)d_in[4];
  // d_in[5] = top_k (== 16, hardcoded)

  char* ws = (char*)d_ws;
  float* G    = (float*)(ws + 0);          //  16384 B
  float* qGT  = (float*)(ws + 16384);      // 262144 B  [64][1024]
  float* qGr  = (float*)(ws + 278528);     // 262144 B  [1024][64]
  float* q2   = (float*)(ws + 540672);     //   4096 B
  float* s2   = (float*)(ws + 544768);     // 524288 B
  float* ir2  = (float*)(ws + 1069056);    // 524288 B
  float* tau  = (float*)(ws + 1593344);    //   4096 B
  int*   cnt  = (int*)(ws + 1597440);      //   4096 B
  float2* cand = (float2*)(ws + 1601536);  // NQ*cap*8 B

  int cap = CAP_DEFAULT;
  if (ws_size > 1601536) {
    size_t avail = (ws_size - 1601536) / ((size_t)NQ * 8);
    if (avail < (size_t)cap) cap = (int)avail;
  }

  float* out = (float*)d_out;

  hipMemsetAsync(cnt, 0, NQ * sizeof(int), stream);
  g_kernel<<<16, 256, 0, stream>>>(M, G);
  q_kernel<<<NQ / 4, 256, 0, stream>>>(query, W, G, qGT, qGr, q2);
  s_kernel<<<NS / NT, 256, 0, stream>>>(stored, resil, G, s2, ir2);
  tau_kernel<<<NQ, 64, 0, stream>>>(stored, qGr, q2, s2, ir2, tau);
  main_kernel<<<dim3(NCHUNK, NQ / QT), 256, 0, stream>>>(
      stored, qGT, q2, s2, ir2, tau, cnt, cand, cap);
  final_kernel<<<NQ, 64, 0, stream>>>(cand, cnt, out, cap);
}

// Round 2
// 409.518 us; speedup vs baseline: 1.3282x; 1.3282x over previous
//
#include <hip/hip_runtime.h>
#include <stdint.h>

// Problem constants (fixed by the reference)
#define NQ 1024
#define NS 131072
#define DMM 2048
#define DCC 64
#define K_TOP 16
#define EPS_RES_F 1e-8f
#define EPS_SQRT_F 1e-12f
#define EPS_A 0.01f       // bf16 hi-only dot abs-error coeff (rigorous bound 0.0085)

#define CAP_MAX 3072      // candidate capacity per query (E=1024, sigma~256 -> +8 sigma)
#define RCAP 256          // refine-set capacity per query

typedef __attribute__((ext_vector_type(8))) short short8v;  // 8 x bf16
typedef __attribute__((ext_vector_type(4))) float f32x4;

__device__ __forceinline__ unsigned short f2bf(float x) {  // RNE f32->bf16
  unsigned u = __float_as_uint(x);
  unsigned r = (u + 0x7FFFu + ((u >> 16) & 1u)) >> 16;
  return (unsigned short)r;
}

__device__ __forceinline__ void gl_lds16(const void* g, void* l) {
  __builtin_amdgcn_global_load_lds(
      (const __attribute__((address_space(1))) unsigned int*)g,
      (__attribute__((address_space(3))) unsigned int*)l, 16, 0, 0);
}

__device__ __forceinline__ bool lex_lt(float ka, int ia, float kb, int ib) {
  return (ka < kb) || (ka == kb && ia < ib);
}

__device__ __forceinline__ void ins16(float key, int idx, float (&k16)[16], int (&i16)[16]) {
  if (lex_lt(key, idx, k16[15], i16[15])) {
#pragma unroll
    for (int s = 15; s >= 1; --s) {
      const bool dprev = lex_lt(key, idx, k16[s - 1], i16[s - 1]);
      const bool dcur = lex_lt(key, idx, k16[s], i16[s]);
      const float nk = dprev ? k16[s - 1] : key;
      const int ni = dprev ? i16[s - 1] : idx;
      if (dcur) { k16[s] = nk; i16[s] = ni; }
    }
    if (lex_lt(key, idx, k16[0], i16[0])) { k16[0] = key; i16[0] = idx; }
  }
}

// ---------------------------------------------------------------- G = M M^T
__global__ __launch_bounds__(256) void g_kernel(const float* __restrict__ M,
                                                float* __restrict__ G) {
  __shared__ __align__(16) float Ml[64 * 66];
  const int t = threadIdx.x;
  for (int p = 0; p < 16; ++p) {
    int i = p * 256 + t;
    Ml[(i >> 6) * 66 + (i & 63)] = M[i];
  }
  __syncthreads();
  const int e = blockIdx.x * 256 + t;
  const int i = e >> 6, j = e & 63;
  float a = 0.f;
#pragma unroll
  for (int k = 0; k < 64; ++k) a = fmaf(Ml[i * 66 + k], Ml[j * 66 + k], a);
  G[e] = a;
}

// ---------------- qc = q W ; qG = qc G ; q2 = qc.qG ; qGh bf16 ; qe = eps*|qG|
__global__ __launch_bounds__(256) void q_kernel(
    const float* __restrict__ query, const float* __restrict__ W,
    const float* __restrict__ G, float* __restrict__ qGT,
    float* __restrict__ qGr, unsigned short* __restrict__ qGh,
    float* __restrict__ q2o, float* __restrict__ qeo) {
  __shared__ __align__(16) float qs[4][DMM];
  __shared__ float part[4][4][64];
  __shared__ float qc[4][64];
  const int t = threadIdx.x;
  const int qb = blockIdx.x * 4;
  {
    const float4* src = reinterpret_cast<const float4*>(query + (size_t)qb * DMM);
    float4* dst = reinterpret_cast<float4*>(&qs[0][0]);
#pragma unroll
    for (int r = 0; r < 8; ++r) dst[r * 256 + t] = src[r * 256 + t];
  }
  __syncthreads();
  const int c = t & 63, seg = t >> 6;
  float p0 = 0.f, p1 = 0.f, p2 = 0.f, p3 = 0.f;
  const int kbase = seg * 512;
  for (int ki = 0; ki < 512; ++ki) {
    const int k = kbase + ki;
    const float w = W[(size_t)k * 64 + c];
    p0 = fmaf(qs[0][k], w, p0);
    p1 = fmaf(qs[1][k], w, p1);
    p2 = fmaf(qs[2][k], w, p2);
    p3 = fmaf(qs[3][k], w, p3);
  }
  part[0][seg][c] = p0; part[1][seg][c] = p1;
  part[2][seg][c] = p2; part[3][seg][c] = p3;
  __syncthreads();
  {
    const int q = t >> 6, cc = t & 63;
    qc[q][cc] = part[q][0][cc] + part[q][1][cc] + part[q][2][cc] + part[q][3][cc];
  }
  __syncthreads();
  const int w = t >> 6, lane = t & 63;
  float g = 0.f;
  for (int j = 0; j < 64; ++j) g = fmaf(qc[w][j], G[j * 64 + lane], g);
  const int q = qb + w;
  qGT[(size_t)lane * NQ + q] = g;
  qGr[(size_t)q * DCC + lane] = g;
  qGh[(size_t)q * DCC + lane] = f2bf(g);
  float pr = qc[w][lane] * g;
  float pn = g * g;
#pragma unroll
  for (int off = 32; off; off >>= 1) {
    pr += __shfl_xor(pr, off);
    pn += __shfl_xor(pn, off);
  }
  if (lane == 0) {
    q2o[q] = pr;
    qeo[q] = EPS_A * sqrtf(pn);
  }
}

// --- s2 = s^T G s ; sb = s2/2 ; sn = |s| ; ir2 ; h = 1/(2 ir2) ; sh bf16 rows
__global__ __launch_bounds__(256) void s_kernel(
    const float* __restrict__ stored, const float* __restrict__ resil,
    const float* __restrict__ G, float* __restrict__ s2o,
    float* __restrict__ sbo, float* __restrict__ sno,
    float* __restrict__ ir2o, float* __restrict__ ho,
    unsigned short* __restrict__ sho) {
  __shared__ __align__(16) float Gl[64 * 66];
  __shared__ __align__(16) float sst[64 * 64];
  __shared__ float part2[64 * 33];
  __shared__ float ps[64 * 33];
  const int t = threadIdx.x;
  const int nb = blockIdx.x * 64;
  for (int p = 0; p < 16; ++p) {
    int i = p * 256 + t;
    Gl[(i >> 6) * 66 + (i & 63)] = G[i];
  }
  {
    const float4* src = reinterpret_cast<const float4*>(stored + (size_t)nb * DCC);
    float4* dst = reinterpret_cast<float4*>(sst);
#pragma unroll
    for (int r = 0; r < 4; ++r) dst[r * 256 + t] = src[r * 256 + t];
  }
  __syncthreads();
  const int l = t & 31, tw = t >> 5;
  float acc0[8], acc1[8];
#pragma unroll
  for (int i = 0; i < 8; ++i) { acc0[i] = 0.f; acc1[i] = 0.f; }
  for (int kb = 0; kb < 16; ++kb) {
    const float2 ga0 = *reinterpret_cast<const float2*>(&Gl[(4 * kb + 0) * 66 + 2 * l]);
    const float2 ga1 = *reinterpret_cast<const float2*>(&Gl[(4 * kb + 1) * 66 + 2 * l]);
    const float2 ga2 = *reinterpret_cast<const float2*>(&Gl[(4 * kb + 2) * 66 + 2 * l]);
    const float2 ga3 = *reinterpret_cast<const float2*>(&Gl[(4 * kb + 3) * 66 + 2 * l]);
#pragma unroll
    for (int i = 0; i < 8; ++i) {
      const float4 sv = *reinterpret_cast<const float4*>(&sst[(8 * tw + i) * 64 + 4 * kb]);
      acc0[i] = fmaf(ga3.x, sv.w, fmaf(ga2.x, sv.z, fmaf(ga1.x, sv.y, fmaf(ga0.x, sv.x, acc0[i]))));
      acc1[i] = fmaf(ga3.y, sv.w, fmaf(ga2.y, sv.z, fmaf(ga1.y, sv.y, fmaf(ga0.y, sv.x, acc1[i]))));
    }
  }
#pragma unroll
  for (int i = 0; i < 8; ++i) {
    const int n = 8 * tw + i;
    const float2 sj = *reinterpret_cast<const float2*>(&sst[n * 64 + 2 * l]);
    part2[n * 33 + l] = acc0[i] * sj.x + acc1[i] * sj.y;
    ps[n * 33 + l] = sj.x * sj.x + sj.y * sj.y;
  }
  __syncthreads();
  // bf16 conversion of the staged tile (coalesced 2B stores)
  for (int p = 0; p < 16; ++p) {
    const int i = p * 256 + t;
    const int nl = i >> 6, k = i & 63;
    sho[(size_t)(nb + nl) * DCC + k] = f2bf(sst[nl * 64 + k]);
  }
  if (t < 64) {
    float s = 0.f, sp = 0.f;
#pragma unroll
    for (int u = 0; u < 32; ++u) { s += part2[t * 33 + u]; sp += ps[t * 33 + u]; }
    s2o[nb + t] = s;
    sbo[nb + t] = 0.5f * s;
    sno[nb + t] = sqrtf(sp);
  } else if (t < 128) {
    const int n = t - 64;
    const float rv = resil[nb + n] + EPS_RES_F;
    const float inv = 1.0f / rv;
    ir2o[nb + n] = inv * inv;
    ho[nb + n] = 0.5f * rv * rv;
  }
}

// --------- exact f32 keys for the 1/64 subsample (rows n = 64*j, j<2048)
// Identical fma chain to the refine pass in final_kernel (bit-exact keys).
__global__ __launch_bounds__(256) void sub_kernel(
    const float* __restrict__ stored, const float* __restrict__ qGT,
    const float* __restrict__ q2g, const float* __restrict__ s2g,
    const float* __restrict__ ir2g, float* __restrict__ skeys) {
  __shared__ __align__(16) float qg[64 * 128];
  __shared__ __align__(16) float sst[64 * 64];
  __shared__ float s2sub[64];
  __shared__ float ir2sub[64];
  const int t = threadIdx.x;
  const int jb = blockIdx.x * 64;      // 32 j-tiles
  const int qbase = blockIdx.y * 128;  // 8 q-tiles
  for (int p = 0; p < 32; ++p) {
    const int i = p * 256 + t;
    const int k = i >> 7, qq = i & 127;
    qg[k * 128 + qq] = qGT[(size_t)k * NQ + qbase + qq];
  }
#pragma unroll
  for (int p = 0; p < 4; ++p) {
    const int idx = p * 256 + t;
    const int r = idx >> 4, f4 = idx & 15;
    reinterpret_cast<float4*>(sst)[r * 16 + f4] =
        reinterpret_cast<const float4*>(stored + (size_t)(64 * (jb + r)) * DCC)[f4];
  }
  if (t < 64) s2sub[t] = s2g[64 * (jb + t)];
  else if (t < 128) ir2sub[t - 64] = ir2g[64 * (jb + t - 64)];
  __syncthreads();
  const int l = t & 31, tw = t >> 5;
  const int q0 = 4 * l;
  float q2r[4];
#pragma unroll
  for (int qq = 0; qq < 4; ++qq) q2r[qq] = q2g[qbase + q0 + qq];
  float acc[4][8];
#pragma unroll
  for (int qq = 0; qq < 4; ++qq)
#pragma unroll
    for (int i = 0; i < 8; ++i) acc[qq][i] = 0.f;
  for (int kb = 0; kb < 16; ++kb) {
    const float4 qa0 = *reinterpret_cast<const float4*>(&qg[(4 * kb + 0) * 128 + q0]);
    const float4 qa1 = *reinterpret_cast<const float4*>(&qg[(4 * kb + 1) * 128 + q0]);
    const float4 qa2 = *reinterpret_cast<const float4*>(&qg[(4 * kb + 2) * 128 + q0]);
    const float4 qa3 = *reinterpret_cast<const float4*>(&qg[(4 * kb + 3) * 128 + q0]);
#pragma unroll
    for (int i = 0; i < 8; ++i) {
      const float4 sv = *reinterpret_cast<const float4*>(&sst[(8 * tw + i) * 64 + 4 * kb]);
      acc[0][i] = fmaf(qa3.x, sv.w, fmaf(qa2.x, sv.z, fmaf(qa1.x, sv.y, fmaf(qa0.x, sv.x, acc[0][i]))));
      acc[1][i] = fmaf(qa3.y, sv.w, fmaf(qa2.y, sv.z, fmaf(qa1.y, sv.y, fmaf(qa0.y, sv.x, acc[1][i]))));
      acc[2][i] = fmaf(qa3.z, sv.w, fmaf(qa2.z, sv.z, fmaf(qa1.z, sv.y, fmaf(qa0.z, sv.x, acc[2][i]))));
      acc[3][i] = fmaf(qa3.w, sv.w, fmaf(qa2.w, sv.z, fmaf(qa1.w, sv.y, fmaf(qa0.w, sv.x, acc[3][i]))));
    }
  }
#pragma unroll
  for (int i = 0; i < 8; ++i) {
    const int jl = 8 * tw + i;
    const float s2v = s2sub[jl];
    const float ir2v = ir2sub[jl];
#pragma unroll
    for (int qq = 0; qq < 4; ++qq) {
      const float d2 = fmaf(-2.f, acc[qq][i], q2r[qq] + s2v);
      const float key = (fmaxf(d2, 0.f) + EPS_SQRT_F) * ir2v;
      skeys[(size_t)(qbase + q0 + qq) * 2048 + jb + jl] = key;
    }
  }
}

// ------------------- tau[q] = 16th smallest subsample key (exact), * 1.0001
__global__ __launch_bounds__(64) void tau_select(
    const float* __restrict__ skeys, float* __restrict__ tau) {
  __shared__ float kbuf[64 * 33];
  const int lane = threadIdx.x;
  const int q = blockIdx.x;
  float lmin = 3.0e38f;
  int lslot = 0;
  for (int i = 0; i < 32; ++i) {
    const float key = skeys[(size_t)q * 2048 + lane + 64 * i];
    kbuf[lane * 33 + i] = key;
    if (key < lmin) { lmin = key; lslot = i; }
  }
  float tau16 = 0.f;
  for (int r = 0; r < 16; ++r) {
    float v = lmin;
    int who = lane;
#pragma unroll
    for (int off = 32; off; off >>= 1) {
      const float ov = __shfl_xor(v, off);
      const int ow = __shfl_xor(who, off);
      if (ov < v || (ov == v && ow < who)) { v = ov; who = ow; }
    }
    tau16 = v;
    if (lane == who) {
      kbuf[lane * 33 + lslot] = 3.0e38f;
      lmin = 3.0e38f; lslot = 0;
      for (int s = 0; s < 32; ++s) {
        const float vv = kbuf[lane * 33 + s];
        if (vv < lmin) { lmin = vv; lslot = s; }
      }
    }
  }
  if (lane == 0) tau[q] = tau16 * 1.0001f;
}

// --------------- MFMA screening pass: bf16-hi cross-GEMM + bounded filter
// accept iff  a >= q2/2 + s2/2 - tau*h - (EPS_A*|qG|)*|s|   (provable superset)
__global__ __launch_bounds__(256, 2) void main_mfma(
    const unsigned short* __restrict__ sh, const unsigned short* __restrict__ qGh,
    const float* __restrict__ q2g, const float* __restrict__ qeg,
    const float* __restrict__ taug, const float* __restrict__ sbg,
    const float* __restrict__ hg, const float* __restrict__ sng,
    const float* __restrict__ ir2g, int* __restrict__ cnt,
    float2* __restrict__ cand, int cap) {
  __shared__ __align__(16) char smA[32768];  // 256 n-rows x 128B bf16, XOR-swizzled
  __shared__ __align__(16) char smB[16384];  // 128 q-rows x 128B bf16, XOR-swizzled
  __shared__ float sbt[256], ht[256], snt[256], ir2t[256];
  const int t = threadIdx.x;
  const int lane = t & 63, w = t >> 6;
  const int l15 = lane & 15, hi4 = (lane >> 4) << 2;
  const int chunk = blockIdx.x;   // 64 chunks; linear%8 == chunk%8 -> XCD pinned
  const int qbase = blockIdx.y * 128;
  // staging source swizzle (inverse of the read swizzle; LDS dest is linear)
  const int sx = ((lane & 7) << 4) ^ ((lane >> 3) << 4);
  // fragment read offsets within a row: k-bytes = ks*64 + (lane>>4)*16, XOR row-swz
  const int g16 = (lane >> 4) << 4, swz = (lane & 7) << 4;
  const int kx0 = g16 ^ swz;
  const int kx1 = (64 | g16) ^ swz;

  // stage B tile (qGh rows qbase..qbase+127) once
#pragma unroll
  for (int ii = 0; ii < 4; ++ii) {
    const int row = w * 32 + ii * 8 + (lane >> 3);
    gl_lds16((const char*)qGh + (size_t)(qbase + row) * 128 + sx,
             smB + w * 4096 + ii * 1024);
  }
  float q2h_r[8], tau_r[8], qe_r[8];
#pragma unroll
  for (int qi = 0; qi < 8; ++qi) {
    const int q = qbase + qi * 16 + l15;
    q2h_r[qi] = 0.5f * q2g[q];
    tau_r[qi] = taug[q];
    qe_r[qi] = qeg[q];
  }
  const f32x4 z4 = {0.f, 0.f, 0.f, 0.f};

  for (int nt = 0; nt < 8; ++nt) {
    const int nb = chunk * 2048 + nt * 256;
    __syncthreads();  // previous tile fully consumed (also covers first-iter B)
#pragma unroll
    for (int ii = 0; ii < 8; ++ii) {
      const int row = w * 64 + ii * 8 + (lane >> 3);
      gl_lds16((const char*)sh + (size_t)(nb + row) * 128 + sx,
               smA + w * 8192 + ii * 1024);
    }
    sbt[t] = sbg[nb + t];
    ht[t] = hg[nb + t];
    snt[t] = sng[nb + t];
    ir2t[t] = ir2g[nb + t];
    __syncthreads();  // drains vmcnt (global_load_lds) + lds writes

    f32x4 acc[4][8];
    {
      short8v bfr[8];
#pragma unroll
      for (int qi = 0; qi < 8; ++qi)
        bfr[qi] = *reinterpret_cast<const short8v*>(smB + ((qi * 16 + l15) << 7) + kx0);
#pragma unroll
      for (int ni = 0; ni < 4; ++ni) {
        const short8v af = *reinterpret_cast<const short8v*>(
            smA + ((w * 64 + ni * 16 + l15) << 7) + kx0);
#pragma unroll
        for (int qi = 0; qi < 8; ++qi)
          acc[ni][qi] = __builtin_amdgcn_mfma_f32_16x16x32_bf16(af, bfr[qi], z4, 0, 0, 0);
      }
#pragma unroll
      for (int qi = 0; qi < 8; ++qi)
        bfr[qi] = *reinterpret_cast<const short8v*>(smB + ((qi * 16 + l15) << 7) + kx1);
#pragma unroll
      for (int ni = 0; ni < 4; ++ni) {
        const short8v af = *reinterpret_cast<const short8v*>(
            smA + ((w * 64 + ni * 16 + l15) << 7) + kx1);
#pragma unroll
        for (int qi = 0; qi < 8; ++qi)
          acc[ni][qi] = __builtin_amdgcn_mfma_f32_16x16x32_bf16(af, bfr[qi], acc[ni][qi], 0, 0, 0);
      }
    }
    // epilogue: bounded filter; C/D map: col(q)=lane&15, row(n)=(lane>>4)*4+reg
#pragma unroll
    for (int ni = 0; ni < 4; ++ni) {
#pragma unroll
      for (int r = 0; r < 4; ++r) {
        const int nl = w * 64 + ni * 16 + hi4 + r;
        const float sbn = sbt[nl], hn = ht[nl], snn = snt[nl];
#pragma unroll
        for (int qi = 0; qi < 8; ++qi) {
          const float a = acc[ni][qi][r];
          const float t1 = q2h_r[qi] + sbn;
          const float thr = fmaf(-qe_r[qi], snn, fmaf(-tau_r[qi], hn, t1));
          if (a >= thr) {
            const float d2 = 2.0f * (t1 - a);
            const float keyp = (fmaxf(d2, 0.0f) + EPS_SQRT_F) * ir2t[nl];
            const int q = qbase + qi * 16 + l15;
            const int pos = atomicAdd(&cnt[q], 1);
            if (pos < cap)
              cand[(size_t)q * cap + pos] = make_float2(keyp, __int_as_float(nb + nl));
          }
        }
      }
    }
  }
}

// ------ final: U16 bracket -> provable containment set R -> exact f32 refine
__global__ __launch_bounds__(64) void final_kernel(
    const float2* __restrict__ cand, const int* __restrict__ cnt,
    const float* __restrict__ qGr, const float* __restrict__ q2g,
    const float* __restrict__ qeg, const float* __restrict__ stored,
    const float* __restrict__ s2g, const float* __restrict__ ir2g,
    const float* __restrict__ sng, float* __restrict__ out, int cap) {
  __shared__ __align__(16) float qgl[64];
  __shared__ float Rk[RCAP];
  __shared__ int Rn[RCAP];
  __shared__ int rc;
  __shared__ float lk[64 * 17];
  __shared__ int li[64 * 17];
  const int lane = threadIdx.x;
  const int q = blockIdx.x;
  qgl[lane] = qGr[(size_t)q * DCC + lane];
  if (lane == 0) rc = 0;
  __syncthreads();
  const float q2v = q2g[q];
  const float qev = qeg[q];
  int c = cnt[q];
  if (c > cap) c = cap;
  float k16[16];
  int i16[16];
#pragma unroll
  for (int s = 0; s < 16; ++s) { k16[s] = 3.0e38f; i16[s] = 0x7FFFFFFF; }
  // pass 1: U16 = 16th smallest upper bound
  for (int i = lane; i < c; i += 64) {
    const float2 kv = cand[(size_t)q * cap + i];
    const int n = __float_as_int(kv.y);
    const float ir2n = ir2g[n];
    const float e = 2.0f * qev * sng[n] * ir2n;
    const float upper = fmaxf(kv.x + e, EPS_SQRT_F * ir2n);
    ins16(upper, n, k16, i16);
  }
#pragma unroll
  for (int s = 0; s < 16; ++s) { lk[lane * 17 + s] = k16[s]; li[lane * 17 + s] = i16[s]; }
  __syncthreads();
  float U16 = 3.0e38f;
  {
    int ptr = 0;
    for (int r = 0; r < K_TOP; ++r) {
      float v = lk[lane * 17 + ptr];
      int id = li[lane * 17 + ptr];
      int who = lane;
#pragma unroll
      for (int off = 32; off; off >>= 1) {
        const float ov = __shfl_xor(v, off);
        const int oid = __shfl_xor(id, off);
        const int ow = __shfl_xor(who, off);
        if (ov < v || (ov == v && oid < id)) { v = ov; id = oid; who = ow; }
      }
      U16 = v;
      if (lane == who) ptr++;
    }
  }
  __syncthreads();
  // pass 2: R = { lower <= U16 }  (contains the exact top-16)
  for (int i = lane; i < c; i += 64) {
    const float2 kv = cand[(size_t)q * cap + i];
    const int n = __float_as_int(kv.y);
    const float e = 2.0f * qev * sng[n] * ir2g[n];
    if (kv.x - e <= U16) {
      const int pos = atomicAdd(&rc, 1);
      if (pos < RCAP) Rn[pos] = n;
    }
  }
  __syncthreads();
  int m = rc;
  if (m > RCAP) m = RCAP;
  // pass 3: exact keys (bit-identical chain to sub_kernel / round-1)
  for (int ri = lane; ri < m; ri += 64) {
    const int n = Rn[ri];
    const float4* srow = reinterpret_cast<const float4*>(stored + (size_t)n * DCC);
    float a = 0.f;
#pragma unroll
    for (int kb = 0; kb < 16; ++kb) {
      const float4 qv = *reinterpret_cast<const float4*>(&qgl[4 * kb]);
      const float4 sv = srow[kb];
      a = fmaf(qv.w, sv.w, fmaf(qv.z, sv.z, fmaf(qv.y, sv.y, fmaf(qv.x, sv.x, a))));
    }
    const float d2 = fmaf(-2.f, a, q2v + s2g[n]);
    Rk[ri] = (fmaxf(d2, 0.f) + EPS_SQRT_F) * ir2g[n];
  }
  __syncthreads();
  // pass 4: exact lexicographic top-16 of R
#pragma unroll
  for (int s = 0; s < 16; ++s) { k16[s] = 3.0e38f; i16[s] = 0x7FFFFFFF; }
  for (int ri = lane; ri < m; ri += 64) ins16(Rk[ri], Rn[ri], k16, i16);
#pragma unroll
  for (int s = 0; s < 16; ++s) { lk[lane * 17 + s] = k16[s]; li[lane * 17 + s] = i16[s]; }
  __syncthreads();
  {
    int ptr = 0;
    for (int r = 0; r < K_TOP; ++r) {
      float v = lk[lane * 17 + ptr];
      int id = li[lane * 17 + ptr];
      int who = lane;
#pragma unroll
      for (int off = 32; off; off >>= 1) {
        const float ov = __shfl_xor(v, off);
        const int oid = __shfl_xor(id, off);
        const int ow = __shfl_xor(who, off);
        if (ov < v || (ov == v && oid < id)) { v = ov; id = oid; who = ow; }
      }
      if (lane == 0) {
        out[q * K_TOP + r] = sqrtf(v);
        out[NQ * K_TOP + q * K_TOP + r] = (float)id;
      }
      if (lane == who) ptr++;
    }
  }
}

// ----------------------------------------------------------------- launcher
extern "C" void kernel_launch(void* const* d_in, const int* in_sizes, int n_in,
                              void* d_out, int out_size, void* d_ws, size_t ws_size,
                              hipStream_t stream) {
  const float* query  = (const float*)d_in[0];
  const float* stored = (const float*)d_in[1];
  const float* resil  = (const float*)d_in[2];
  const float* W      = (const float*)d_in[3];
  const float* M      = (const float*)d_in[4];

  char* ws = (char*)d_ws;
  size_t off = 0;
  float* G    = (float*)(ws + off); off += 16384;
  float* qGT  = (float*)(ws + off); off += 262144;   // [64][1024] f32 (sub_kernel)
  float* qGr  = (float*)(ws + off); off += 262144;   // [1024][64] f32 (final)
  unsigned short* qGh = (unsigned short*)(ws + off); off += 131072;  // bf16 [1024][64]
  float* q2   = (float*)(ws + off); off += 4096;
  float* qe   = (float*)(ws + off); off += 4096;
  float* tau  = (float*)(ws + off); off += 4096;
  float* s2   = (float*)(ws + off); off += 524288;
  float* sb   = (float*)(ws + off); off += 524288;
  float* h    = (float*)(ws + off); off += 524288;
  float* sn   = (float*)(ws + off); off += 524288;
  float* ir2  = (float*)(ws + off); off += 524288;
  int*   cnt  = (int*)(ws + off);   off += 4096;
  unsigned short* sh = (unsigned short*)(ws + off); off += 16777216;  // bf16 [131072][64]
  float2* cand = (float2*)(ws + off);           // cap*8*1024 bytes
  float*  skeys = (float*)cand;                 // overlay: used before cand is written

  int cap = CAP_MAX;
  if (ws_size > off) {
    size_t avail = (ws_size - off) / ((size_t)NQ * 8);
    if (avail < (size_t)cap) cap = (int)avail;
  }
  if (cap < 256) cap = 256;

  float* out = (float*)d_out;

  hipMemsetAsync(cnt, 0, NQ * sizeof(int), stream);
  g_kernel<<<16, 256, 0, stream>>>(M, G);
  q_kernel<<<NQ / 4, 256, 0, stream>>>(query, W, G, qGT, qGr, qGh, q2, qe);
  s_kernel<<<NS / 64, 256, 0, stream>>>(stored, resil, G, s2, sb, sn, ir2, h, sh);
  sub_kernel<<<dim3(32, 8), 256, 0, stream>>>(stored, qGT, q2, s2, ir2, skeys);
  tau_select<<<NQ, 64, 0, stream>>>(skeys, tau);
  main_mfma<<<dim3(64, 8), 256, 0, stream>>>(sh, qGh, q2, qe, tau, sb, h, sn, ir2,
                                             cnt, cand, cap);
  final_kernel<<<NQ, 64, 0, stream>>>(cand, cnt, qGr, q2, qe, stored, s2, ir2, sn,
                                      out, cap);
}

// Round 3
// 392.055 us; speedup vs baseline: 1.3873x; 1.0445x over previous
//
#include <hip/hip_runtime.h>
#include <stdint.h>

// Problem constants (fixed by the reference)
#define NQ 1024
#define NS 131072
#define DMM 2048
#define DCC 64
#define K_TOP 16
#define EPS_RES_F 1e-8f
#define EPS_SQRT_F 1e-12f
#define EPS_A 0.01f       // bf16 hi-only dot abs-error coeff (rigorous bound ~0.004)

#define OVCAP 8192        // global overflow list capacity (normally unused)

typedef __attribute__((ext_vector_type(8))) short short8v;  // 8 x bf16
typedef __attribute__((ext_vector_type(4))) float f32x4;

__device__ __forceinline__ unsigned short f2bf(float x) {  // RNE f32->bf16
  unsigned u = __float_as_uint(x);
  unsigned r = (u + 0x7FFFu + ((u >> 16) & 1u)) >> 16;
  return (unsigned short)r;
}

__device__ __forceinline__ void gl_lds16(const void* g, void* l) {
  __builtin_amdgcn_global_load_lds(
      (const __attribute__((address_space(1))) unsigned int*)g,
      (__attribute__((address_space(3))) unsigned int*)l, 16, 0, 0);
}

__device__ __forceinline__ bool lex_lt(float ka, int ia, float kb, int ib) {
  return (ka < kb) || (ka == kb && ia < ib);
}

__device__ __forceinline__ void ins16(float key, int idx, float (&k16)[16], int (&i16)[16]) {
  if (lex_lt(key, idx, k16[15], i16[15])) {
#pragma unroll
    for (int s = 15; s >= 1; --s) {
      const bool dprev = lex_lt(key, idx, k16[s - 1], i16[s - 1]);
      const bool dcur = lex_lt(key, idx, k16[s], i16[s]);
      const float nk = dprev ? k16[s - 1] : key;
      const int ni = dprev ? i16[s - 1] : idx;
      if (dcur) { k16[s] = nk; i16[s] = ni; }
    }
    if (lex_lt(key, idx, k16[0], i16[0])) { k16[0] = key; i16[0] = idx; }
  }
}

// exact key chain — MUST stay bit-identical to sub_kernel's accumulation
__device__ __forceinline__ float exact_key(const float* __restrict__ stored,
                                           const float* qgl, float q2v,
                                           const float* __restrict__ s2g,
                                           const float* __restrict__ ir2g, int n) {
  const float4* srow = reinterpret_cast<const float4*>(stored + (size_t)n * DCC);
  float a = 0.f;
#pragma unroll
  for (int kb = 0; kb < 16; ++kb) {
    const float4 qv = *reinterpret_cast<const float4*>(&qgl[4 * kb]);
    const float4 sv = srow[kb];
    a = fmaf(qv.w, sv.w, fmaf(qv.z, sv.z, fmaf(qv.y, sv.y, fmaf(qv.x, sv.x, a))));
  }
  const float d2 = fmaf(-2.f, a, q2v + s2g[n]);
  return (fmaxf(d2, 0.f) + EPS_SQRT_F) * ir2g[n];
}

// ---------------------------------------------------------------- G = M M^T
__global__ __launch_bounds__(256) void g_kernel(const float* __restrict__ M,
                                                float* __restrict__ G) {
  __shared__ __align__(16) float Ml[64 * 66];
  const int t = threadIdx.x;
  for (int p = 0; p < 16; ++p) {
    int i = p * 256 + t;
    Ml[(i >> 6) * 66 + (i & 63)] = M[i];
  }
  __syncthreads();
  const int e = blockIdx.x * 256 + t;
  const int i = e >> 6, j = e & 63;
  float a = 0.f;
#pragma unroll
  for (int k = 0; k < 64; ++k) a = fmaf(Ml[i * 66 + k], Ml[j * 66 + k], a);
  G[e] = a;
}

// ---------------- qc = q W ; qG = qc G ; q2 = qc.qG ; qGh bf16 ; qe = eps*|qG|
__global__ __launch_bounds__(256) void q_kernel(
    const float* __restrict__ query, const float* __restrict__ W,
    const float* __restrict__ G, float* __restrict__ qGT,
    float* __restrict__ qGr, unsigned short* __restrict__ qGh,
    float* __restrict__ q2o, float* __restrict__ qeo) {
  __shared__ __align__(16) float qs[4][DMM];
  __shared__ float part[4][4][64];
  __shared__ float qc[4][64];
  const int t = threadIdx.x;
  const int qb = blockIdx.x * 4;
  {
    const float4* src = reinterpret_cast<const float4*>(query + (size_t)qb * DMM);
    float4* dst = reinterpret_cast<float4*>(&qs[0][0]);
#pragma unroll
    for (int r = 0; r < 8; ++r) dst[r * 256 + t] = src[r * 256 + t];
  }
  __syncthreads();
  const int c = t & 63, seg = t >> 6;
  float p0 = 0.f, p1 = 0.f, p2 = 0.f, p3 = 0.f;
  const int kbase = seg * 512;
  for (int ki = 0; ki < 512; ++ki) {
    const int k = kbase + ki;
    const float w = W[(size_t)k * 64 + c];
    p0 = fmaf(qs[0][k], w, p0);
    p1 = fmaf(qs[1][k], w, p1);
    p2 = fmaf(qs[2][k], w, p2);
    p3 = fmaf(qs[3][k], w, p3);
  }
  part[0][seg][c] = p0; part[1][seg][c] = p1;
  part[2][seg][c] = p2; part[3][seg][c] = p3;
  __syncthreads();
  {
    const int q = t >> 6, cc = t & 63;
    qc[q][cc] = part[q][0][cc] + part[q][1][cc] + part[q][2][cc] + part[q][3][cc];
  }
  __syncthreads();
  const int w = t >> 6, lane = t & 63;
  float g = 0.f;
  for (int j = 0; j < 64; ++j) g = fmaf(qc[w][j], G[j * 64 + lane], g);
  const int q = qb + w;
  qGT[(size_t)lane * NQ + q] = g;
  qGr[(size_t)q * DCC + lane] = g;
  qGh[(size_t)q * DCC + lane] = f2bf(g);
  float pr = qc[w][lane] * g;
  float pn = g * g;
#pragma unroll
  for (int off = 32; off; off >>= 1) {
    pr += __shfl_xor(pr, off);
    pn += __shfl_xor(pn, off);
  }
  if (lane == 0) {
    q2o[q] = pr;
    qeo[q] = EPS_A * sqrtf(pn);
  }
}

// ------- s2 = s^T G s ; sn = |s| ; ir2 = 1/(res+eps)^2 ; h = (res+eps)^2/2 ; sh bf16
__global__ __launch_bounds__(256) void s_kernel(
    const float* __restrict__ stored, const float* __restrict__ resil,
    const float* __restrict__ G, float* __restrict__ s2o,
    float* __restrict__ sno, float* __restrict__ ir2o,
    float* __restrict__ ho, unsigned short* __restrict__ sho) {
  __shared__ __align__(16) float Gl[64 * 66];
  __shared__ __align__(16) float sst[64 * 64];
  __shared__ float part2[64 * 33];
  __shared__ float ps[64 * 33];
  const int t = threadIdx.x;
  const int nb = blockIdx.x * 64;
  for (int p = 0; p < 16; ++p) {
    int i = p * 256 + t;
    Gl[(i >> 6) * 66 + (i & 63)] = G[i];
  }
  {
    const float4* src = reinterpret_cast<const float4*>(stored + (size_t)nb * DCC);
    float4* dst = reinterpret_cast<float4*>(sst);
#pragma unroll
    for (int r = 0; r < 4; ++r) dst[r * 256 + t] = src[r * 256 + t];
  }
  __syncthreads();
  const int l = t & 31, tw = t >> 5;
  float acc0[8], acc1[8];
#pragma unroll
  for (int i = 0; i < 8; ++i) { acc0[i] = 0.f; acc1[i] = 0.f; }
  for (int kb = 0; kb < 16; ++kb) {
    const float2 ga0 = *reinterpret_cast<const float2*>(&Gl[(4 * kb + 0) * 66 + 2 * l]);
    const float2 ga1 = *reinterpret_cast<const float2*>(&Gl[(4 * kb + 1) * 66 + 2 * l]);
    const float2 ga2 = *reinterpret_cast<const float2*>(&Gl[(4 * kb + 2) * 66 + 2 * l]);
    const float2 ga3 = *reinterpret_cast<const float2*>(&Gl[(4 * kb + 3) * 66 + 2 * l]);
#pragma unroll
    for (int i = 0; i < 8; ++i) {
      const float4 sv = *reinterpret_cast<const float4*>(&sst[(8 * tw + i) * 64 + 4 * kb]);
      acc0[i] = fmaf(ga3.x, sv.w, fmaf(ga2.x, sv.z, fmaf(ga1.x, sv.y, fmaf(ga0.x, sv.x, acc0[i]))));
      acc1[i] = fmaf(ga3.y, sv.w, fmaf(ga2.y, sv.z, fmaf(ga1.y, sv.y, fmaf(ga0.y, sv.x, acc1[i]))));
    }
  }
#pragma unroll
  for (int i = 0; i < 8; ++i) {
    const int n = 8 * tw + i;
    const float2 sj = *reinterpret_cast<const float2*>(&sst[n * 64 + 2 * l]);
    part2[n * 33 + l] = acc0[i] * sj.x + acc1[i] * sj.y;
    ps[n * 33 + l] = sj.x * sj.x + sj.y * sj.y;
  }
  __syncthreads();
  for (int p = 0; p < 16; ++p) {
    const int i = p * 256 + t;
    const int nl = i >> 6, k = i & 63;
    sho[(size_t)(nb + nl) * DCC + k] = f2bf(sst[nl * 64 + k]);
  }
  if (t < 64) {
    float s = 0.f, sp = 0.f;
#pragma unroll
    for (int u = 0; u < 32; ++u) { s += part2[t * 33 + u]; sp += ps[t * 33 + u]; }
    s2o[nb + t] = s;
    sno[nb + t] = sqrtf(sp);
  } else if (t < 128) {
    const int n = t - 64;
    const float rv = resil[nb + n] + EPS_RES_F;
    const float inv = 1.0f / rv;
    ir2o[nb + n] = inv * inv;
    ho[nb + n] = 0.5f * rv * rv;
  }
}

// --------- exact f32 keys for the 1/64 subsample (rows n = 64*j, j<2048)
__global__ __launch_bounds__(256) void sub_kernel(
    const float* __restrict__ stored, const float* __restrict__ qGT,
    const float* __restrict__ q2g, const float* __restrict__ s2g,
    const float* __restrict__ ir2g, float* __restrict__ skeys) {
  __shared__ __align__(16) float qg[64 * 128];
  __shared__ __align__(16) float sst[64 * 64];
  __shared__ float s2sub[64];
  __shared__ float ir2sub[64];
  const int t = threadIdx.x;
  const int jb = blockIdx.x * 64;
  const int qbase = blockIdx.y * 128;
  for (int p = 0; p < 32; ++p) {
    const int i = p * 256 + t;
    const int k = i >> 7, qq = i & 127;
    qg[k * 128 + qq] = qGT[(size_t)k * NQ + qbase + qq];
  }
#pragma unroll
  for (int p = 0; p < 4; ++p) {
    const int idx = p * 256 + t;
    const int r = idx >> 4, f4 = idx & 15;
    reinterpret_cast<float4*>(sst)[r * 16 + f4] =
        reinterpret_cast<const float4*>(stored + (size_t)(64 * (jb + r)) * DCC)[f4];
  }
  if (t < 64) s2sub[t] = s2g[64 * (jb + t)];
  else if (t < 128) ir2sub[t - 64] = ir2g[64 * (jb + t - 64)];
  __syncthreads();
  const int l = t & 31, tw = t >> 5;
  const int q0 = 4 * l;
  float q2r[4];
#pragma unroll
  for (int qq = 0; qq < 4; ++qq) q2r[qq] = q2g[qbase + q0 + qq];
  float acc[4][8];
#pragma unroll
  for (int qq = 0; qq < 4; ++qq)
#pragma unroll
    for (int i = 0; i < 8; ++i) acc[qq][i] = 0.f;
  for (int kb = 0; kb < 16; ++kb) {
    const float4 qa0 = *reinterpret_cast<const float4*>(&qg[(4 * kb + 0) * 128 + q0]);
    const float4 qa1 = *reinterpret_cast<const float4*>(&qg[(4 * kb + 1) * 128 + q0]);
    const float4 qa2 = *reinterpret_cast<const float4*>(&qg[(4 * kb + 2) * 128 + q0]);
    const float4 qa3 = *reinterpret_cast<const float4*>(&qg[(4 * kb + 3) * 128 + q0]);
#pragma unroll
    for (int i = 0; i < 8; ++i) {
      const float4 sv = *reinterpret_cast<const float4*>(&sst[(8 * tw + i) * 64 + 4 * kb]);
      acc[0][i] = fmaf(qa3.x, sv.w, fmaf(qa2.x, sv.z, fmaf(qa1.x, sv.y, fmaf(qa0.x, sv.x, acc[0][i]))));
      acc[1][i] = fmaf(qa3.y, sv.w, fmaf(qa2.y, sv.z, fmaf(qa1.y, sv.y, fmaf(qa0.y, sv.x, acc[1][i]))));
      acc[2][i] = fmaf(qa3.z, sv.w, fmaf(qa2.z, sv.z, fmaf(qa1.z, sv.y, fmaf(qa0.z, sv.x, acc[2][i]))));
      acc[3][i] = fmaf(qa3.w, sv.w, fmaf(qa2.w, sv.z, fmaf(qa1.w, sv.y, fmaf(qa0.w, sv.x, acc[3][i]))));
    }
  }
#pragma unroll
  for (int i = 0; i < 8; ++i) {
    const int jl = 8 * tw + i;
    const float s2v = s2sub[jl];
    const float ir2v = ir2sub[jl];
#pragma unroll
    for (int qq = 0; qq < 4; ++qq) {
      const float d2 = fmaf(-2.f, acc[qq][i], q2r[qq] + s2v);
      const float key = (fmaxf(d2, 0.f) + EPS_SQRT_F) * ir2v;
      skeys[(size_t)(qbase + q0 + qq) * 2048 + jb + jl] = key;
    }
  }
}

// ---- tau[q] = 16th smallest subsample key (exact), *1.0001 margin
// per-lane sorted top-16 insert + ptr merge (no divergent rescans)
__global__ __launch_bounds__(64) void tau_select(
    const float* __restrict__ skeys, float* __restrict__ tau) {
  __shared__ float lk[64 * 17];
  const int lane = threadIdx.x;
  const int q = blockIdx.x;
  float k16[16];
#pragma unroll
  for (int s = 0; s < 16; ++s) k16[s] = 3.0e38f;
  for (int i = 0; i < 32; ++i) {
    const float key = skeys[(size_t)q * 2048 + lane + 64 * i];
    if (key < k16[15]) {
#pragma unroll
      for (int s = 15; s >= 1; --s) {
        const bool dprev = key < k16[s - 1];
        const float nk = dprev ? k16[s - 1] : key;
        if (key < k16[s]) k16[s] = nk;
      }
      if (key < k16[0]) k16[0] = key;
    }
  }
#pragma unroll
  for (int s = 0; s < 16; ++s) lk[lane * 17 + s] = k16[s];
  __syncthreads();
  int ptr = 0;
  float tau16 = 0.f;
  for (int r = 0; r < K_TOP; ++r) {
    float v = lk[lane * 17 + ptr];
    int who = lane;
#pragma unroll
    for (int off = 32; off; off >>= 1) {
      const float ov = __shfl_xor(v, off);
      const int ow = __shfl_xor(who, off);
      if (ov < v || (ov == v && ow < who)) { v = ov; who = ow; }
    }
    tau16 = v;
    if (lane == who) ptr++;
  }
  if (lane == 0) tau[q] = tau16 * 1.0001f;
}

// --------------- MFMA screening pass: bf16-hi cross-GEMM + bounded filter
// accept iff  a >= q2/2 + s2/2 - tau*h - (EPS_A*|qG|)*|s|   (provable superset)
// accepts recorded as row indices in block-owned segments; LDS counters only.
__global__ __launch_bounds__(256, 2) void main_mfma(
    const unsigned short* __restrict__ sh, const unsigned short* __restrict__ qGh,
    const float* __restrict__ q2g, const float* __restrict__ qeg,
    const float* __restrict__ taug, const float* __restrict__ s2g,
    const float* __restrict__ hg, const float* __restrict__ sng,
    int* __restrict__ ccnt, int* __restrict__ ovcnt,
    unsigned int* __restrict__ ovf, unsigned int* __restrict__ candIdx,
    int slots) {
  __shared__ __align__(16) char smA[32768];  // 256 n-rows x 128B bf16, XOR-swizzled
  __shared__ __align__(16) char smB[16384];  // 128 q-rows x 128B bf16, XOR-swizzled
  __shared__ float s2t[256], ht[256], snt[256];
  __shared__ int cnt128[128];
  const int t = threadIdx.x;
  const int lane = t & 63, w = t >> 6;
  const int l15 = lane & 15, hi4 = (lane >> 4) << 2;
  const int chunk = blockIdx.x;   // 0..63 (linear%8 == chunk%8 -> XCD pinned)
  const int qbase = blockIdx.y * 128;
  const int sx = ((lane & 7) << 4) ^ ((lane >> 3) << 4);
  const int g16 = (lane >> 4) << 4, swz = (lane & 7) << 4;
  const int kx0 = g16 ^ swz;
  const int kx1 = (64 | g16) ^ swz;

  if (t < 128) cnt128[t] = 0;
#pragma unroll
  for (int ii = 0; ii < 4; ++ii) {
    const int row = w * 32 + ii * 8 + (lane >> 3);
    gl_lds16((const char*)qGh + (size_t)(qbase + row) * 128 + sx,
             smB + w * 4096 + ii * 1024);
  }
  float q2h_r[8], tau_r[8], qe_r[8];
#pragma unroll
  for (int qi = 0; qi < 8; ++qi) {
    const int q = qbase + qi * 16 + l15;
    q2h_r[qi] = 0.5f * q2g[q];
    tau_r[qi] = taug[q];
    qe_r[qi] = qeg[q];
  }
  const f32x4 z4 = {0.f, 0.f, 0.f, 0.f};

  for (int nt = 0; nt < 8; ++nt) {
    const int nb = chunk * 2048 + nt * 256;
    __syncthreads();
#pragma unroll
    for (int ii = 0; ii < 8; ++ii) {
      const int row = w * 64 + ii * 8 + (lane >> 3);
      gl_lds16((const char*)sh + (size_t)(nb + row) * 128 + sx,
               smA + w * 8192 + ii * 1024);
    }
    s2t[t] = s2g[nb + t];
    ht[t] = hg[nb + t];
    snt[t] = sng[nb + t];
    __syncthreads();

    f32x4 acc[4][8];
    {
      short8v bfr[8];
#pragma unroll
      for (int qi = 0; qi < 8; ++qi)
        bfr[qi] = *reinterpret_cast<const short8v*>(smB + ((qi * 16 + l15) << 7) + kx0);
#pragma unroll
      for (int ni = 0; ni < 4; ++ni) {
        const short8v af = *reinterpret_cast<const short8v*>(
            smA + ((w * 64 + ni * 16 + l15) << 7) + kx0);
#pragma unroll
        for (int qi = 0; qi < 8; ++qi)
          acc[ni][qi] = __builtin_amdgcn_mfma_f32_16x16x32_bf16(af, bfr[qi], z4, 0, 0, 0);
      }
#pragma unroll
      for (int qi = 0; qi < 8; ++qi)
        bfr[qi] = *reinterpret_cast<const short8v*>(smB + ((qi * 16 + l15) << 7) + kx1);
#pragma unroll
      for (int ni = 0; ni < 4; ++ni) {
        const short8v af = *reinterpret_cast<const short8v*>(
            smA + ((w * 64 + ni * 16 + l15) << 7) + kx1);
#pragma unroll
        for (int qi = 0; qi < 8; ++qi)
          acc[ni][qi] = __builtin_amdgcn_mfma_f32_16x16x32_bf16(af, bfr[qi], acc[ni][qi], 0, 0, 0);
      }
    }
    // epilogue: C/D map col(q)=lane&15, row(n)=(lane>>4)*4+reg
#pragma unroll
    for (int ni = 0; ni < 4; ++ni) {
#pragma unroll
      for (int r = 0; r < 4; ++r) {
        const int nl = w * 64 + ni * 16 + hi4 + r;
        const float s2n = s2t[nl], hn = ht[nl], snn = snt[nl];
#pragma unroll
        for (int qi = 0; qi < 8; ++qi) {
          const float a = acc[ni][qi][r];
          const float t1 = fmaf(0.5f, s2n, q2h_r[qi]);
          const float thr = fmaf(-qe_r[qi], snn, fmaf(-tau_r[qi], hn, t1));
          if (a >= thr) {
            const int ql = qi * 16 + l15;
            const int n = nb + nl;
            const int pos = atomicAdd(&cnt128[ql], 1);   // LDS atomic (fast)
            if (pos < slots) {
              candIdx[((size_t)((qbase + ql) * 64 + chunk)) * slots + pos] = (unsigned)n;
            } else {
              const int gp = atomicAdd(ovcnt, 1);        // global, ~never
              if (gp < OVCAP) ovf[gp] = ((unsigned)(qbase + ql) << 17) | (unsigned)n;
            }
          }
        }
      }
    }
  }
  __syncthreads();
  if (t < 128) {
    int c = cnt128[t];
    if (c > slots) c = slots;
    ccnt[(size_t)(qbase + t) * 64 + chunk] = c;
  }
}

// ------ final: exact f32 refine of EVERY candidate, lexicographic top-16
__global__ __launch_bounds__(64) void final_kernel(
    const unsigned int* __restrict__ candIdx, const int* __restrict__ ccnt,
    const int* __restrict__ ovcnt, const unsigned int* __restrict__ ovf,
    const float* __restrict__ qGr, const float* __restrict__ q2g,
    const float* __restrict__ stored, const float* __restrict__ s2g,
    const float* __restrict__ ir2g, float* __restrict__ out, int slots) {
  __shared__ __align__(16) float qgl[64];
  __shared__ int ccl[64];
  __shared__ float lk[64 * 17];
  __shared__ int li[64 * 17];
  const int lane = threadIdx.x;
  const int q = blockIdx.x;
  qgl[lane] = qGr[(size_t)q * DCC + lane];
  ccl[lane] = min(ccnt[(size_t)q * 64 + lane], slots);
  __syncthreads();
  const float q2v = q2g[q];
  float k16[16];
  int i16[16];
#pragma unroll
  for (int s = 0; s < 16; ++s) { k16[s] = 3.0e38f; i16[s] = 0x7FFFFFFF; }
  for (int k = 0; k < 64; ++k) {
    const int c = ccl[k];
    if (lane < c) {
      const int n = (int)candIdx[((size_t)(q * 64 + k)) * slots + lane];
      const float key = exact_key(stored, qgl, q2v, s2g, ir2g, n);
      ins16(key, n, k16, i16);
    }
  }
  {  // overflow list (normally empty)
    int oc = *ovcnt;
    if (oc > OVCAP) oc = OVCAP;
    for (int i = lane; i < oc; i += 64) {
      const unsigned pk = ovf[i];
      if ((int)(pk >> 17) == q) {
        const int n = (int)(pk & 0x1FFFFu);
        const float key = exact_key(stored, qgl, q2v, s2g, ir2g, n);
        ins16(key, n, k16, i16);
      }
    }
  }
#pragma unroll
  for (int s = 0; s < 16; ++s) { lk[lane * 17 + s] = k16[s]; li[lane * 17 + s] = i16[s]; }
  __syncthreads();
  int ptr = 0;
  for (int r = 0; r < K_TOP; ++r) {
    float v = lk[lane * 17 + ptr];
    int id = li[lane * 17 + ptr];
    int who = lane;
#pragma unroll
    for (int off = 32; off; off >>= 1) {
      const float ov = __shfl_xor(v, off);
      const int oid = __shfl_xor(id, off);
      const int ow = __shfl_xor(who, off);
      if (ov < v || (ov == v && oid < id)) { v = ov; id = oid; who = ow; }
    }
    if (lane == 0) {
      out[q * K_TOP + r] = sqrtf(v);
      out[NQ * K_TOP + q * K_TOP + r] = (float)id;
    }
    if (lane == who) ptr++;
  }
}

// ----------------------------------------------------------------- launcher
extern "C" void kernel_launch(void* const* d_in, const int* in_sizes, int n_in,
                              void* d_out, int out_size, void* d_ws, size_t ws_size,
                              hipStream_t stream) {
  const float* query  = (const float*)d_in[0];
  const float* stored = (const float*)d_in[1];
  const float* resil  = (const float*)d_in[2];
  const float* W      = (const float*)d_in[3];
  const float* M      = (const float*)d_in[4];

  char* ws = (char*)d_ws;
  size_t off = 0;
  float* G    = (float*)(ws + off); off += 16384;
  float* qGT  = (float*)(ws + off); off += 262144;   // [64][1024] f32
  float* qGr  = (float*)(ws + off); off += 262144;   // [1024][64] f32
  unsigned short* qGh = (unsigned short*)(ws + off); off += 131072;  // bf16
  float* q2   = (float*)(ws + off); off += 4096;
  float* qe   = (float*)(ws + off); off += 4096;
  float* tau  = (float*)(ws + off); off += 4096;
  float* s2   = (float*)(ws + off); off += 524288;
  float* h    = (float*)(ws + off); off += 524288;
  float* sn   = (float*)(ws + off); off += 524288;
  float* ir2  = (float*)(ws + off); off += 524288;
  int*   ccnt = (int*)(ws + off);   off += 262144;   // [1024][64]
  int*   ovcnt = (int*)(ws + off);  off += 4096;
  unsigned int* ovf = (unsigned int*)(ws + off); off += 32768;  // 8192 entries
  unsigned short* sh = (unsigned short*)(ws + off); off += 16777216;  // bf16 rows
  unsigned int* candIdx = (unsigned int*)(ws + off);  // [1024][64][slots] u32
  float* skeys = (float*)candIdx;  // overlay (8 MB, used before candIdx)

  int slots = 64;
  if (ws_size < off + (size_t)NQ * 64 * 64 * 4) slots = 32;

  float* out = (float*)d_out;

  hipMemsetAsync(ovcnt, 0, 4096, stream);
  g_kernel<<<16, 256, 0, stream>>>(M, G);
  q_kernel<<<NQ / 4, 256, 0, stream>>>(query, W, G, qGT, qGr, qGh, q2, qe);
  s_kernel<<<NS / 64, 256, 0, stream>>>(stored, resil, G, s2, sn, ir2, h, sh);
  sub_kernel<<<dim3(32, 8), 256, 0, stream>>>(stored, qGT, q2, s2, ir2, skeys);
  tau_select<<<NQ, 64, 0, stream>>>(skeys, tau);
  main_mfma<<<dim3(64, 8), 256, 0, stream>>>(sh, qGh, q2, qe, tau, s2, h, sn,
                                             ccnt, ovcnt, ovf, candIdx, slots);
  final_kernel<<<NQ, 64, 0, stream>>>(candIdx, ccnt, ovcnt, ovf, qGr, q2,
                                      stored, s2, ir2, out, slots);
}

// Round 4
// 305.198 us; speedup vs baseline: 1.7822x; 1.2846x over previous
//
#include <hip/hip_runtime.h>
#include <stdint.h>

// Problem constants (fixed by the reference)
#define NQ 1024
#define NS 131072
#define DMM 2048
#define DCC 64
#define K_TOP 16
#define EPS_RES_F 1e-8f
#define EPS_SQRT_F 1e-12f
#define EPS_A 0.01f       // bf16 hi-only dot abs-error coeff (rigorous bound ~0.004)

#define OVCAP 8192        // global overflow list capacity (normally unused)
#define MCAP 4096         // max candidates per query = 64 chunks * 64 slots

typedef __attribute__((ext_vector_type(8))) short short8v;  // 8 x bf16
typedef __attribute__((ext_vector_type(4))) float f32x4;

__device__ __forceinline__ unsigned short f2bf(float x) {  // RNE f32->bf16
  unsigned u = __float_as_uint(x);
  unsigned r = (u + 0x7FFFu + ((u >> 16) & 1u)) >> 16;
  return (unsigned short)r;
}

__device__ __forceinline__ void gl_lds16(const void* g, void* l) {
  __builtin_amdgcn_global_load_lds(
      (const __attribute__((address_space(1))) unsigned int*)g,
      (__attribute__((address_space(3))) unsigned int*)l, 16, 0, 0);
}

__device__ __forceinline__ bool lex_lt(float ka, int ia, float kb, int ib) {
  return (ka < kb) || (ka == kb && ia < ib);
}

__device__ __forceinline__ void ins16(float key, int idx, float (&k16)[16], int (&i16)[16]) {
  if (lex_lt(key, idx, k16[15], i16[15])) {
#pragma unroll
    for (int s = 15; s >= 1; --s) {
      const bool dprev = lex_lt(key, idx, k16[s - 1], i16[s - 1]);
      const bool dcur = lex_lt(key, idx, k16[s], i16[s]);
      const float nk = dprev ? k16[s - 1] : key;
      const int ni = dprev ? i16[s - 1] : idx;
      if (dcur) { k16[s] = nk; i16[s] = ni; }
    }
    if (lex_lt(key, idx, k16[0], i16[0])) { k16[0] = key; i16[0] = idx; }
  }
}

// exact key chain — MUST stay bit-identical to sub_kernel's accumulation
__device__ __forceinline__ float exact_key(const float* __restrict__ stored,
                                           const float* qgl, float q2v,
                                           const float* __restrict__ s2g,
                                           const float* __restrict__ ir2g, int n) {
  const float4* srow = reinterpret_cast<const float4*>(stored + (size_t)n * DCC);
  float a = 0.f;
#pragma unroll
  for (int kb = 0; kb < 16; ++kb) {
    const float4 qv = *reinterpret_cast<const float4*>(&qgl[4 * kb]);
    const float4 sv = srow[kb];
    a = fmaf(qv.w, sv.w, fmaf(qv.z, sv.z, fmaf(qv.y, sv.y, fmaf(qv.x, sv.x, a))));
  }
  const float d2 = fmaf(-2.f, a, q2v + s2g[n]);
  return (fmaxf(d2, 0.f) + EPS_SQRT_F) * ir2g[n];
}

// ---------------------------------------------------------------- G = M M^T
__global__ __launch_bounds__(256) void g_kernel(const float* __restrict__ M,
                                                float* __restrict__ G) {
  __shared__ __align__(16) float Ml[64 * 66];
  const int t = threadIdx.x;
  for (int p = 0; p < 16; ++p) {
    int i = p * 256 + t;
    Ml[(i >> 6) * 66 + (i & 63)] = M[i];
  }
  __syncthreads();
  const int e = blockIdx.x * 256 + t;
  const int i = e >> 6, j = e & 63;
  float a = 0.f;
#pragma unroll
  for (int k = 0; k < 64; ++k) a = fmaf(Ml[i * 66 + k], Ml[j * 66 + k], a);
  G[e] = a;
}

// ---------------- qc = q W ; qG = qc G ; q2 = qc.qG ; qGh bf16 ; qe = eps*|qG|
__global__ __launch_bounds__(256) void q_kernel(
    const float* __restrict__ query, const float* __restrict__ W,
    const float* __restrict__ G, float* __restrict__ qGT,
    float* __restrict__ qGr, unsigned short* __restrict__ qGh,
    float* __restrict__ q2o, float* __restrict__ qeo) {
  __shared__ __align__(16) float qs[4][DMM];
  __shared__ float part[4][4][64];
  __shared__ float qc[4][64];
  const int t = threadIdx.x;
  const int qb = blockIdx.x * 4;
  {
    const float4* src = reinterpret_cast<const float4*>(query + (size_t)qb * DMM);
    float4* dst = reinterpret_cast<float4*>(&qs[0][0]);
#pragma unroll
    for (int r = 0; r < 8; ++r) dst[r * 256 + t] = src[r * 256 + t];
  }
  __syncthreads();
  const int c = t & 63, seg = t >> 6;
  float p0 = 0.f, p1 = 0.f, p2 = 0.f, p3 = 0.f;
  const int kbase = seg * 512;
  for (int ki = 0; ki < 512; ++ki) {
    const int k = kbase + ki;
    const float w = W[(size_t)k * 64 + c];
    p0 = fmaf(qs[0][k], w, p0);
    p1 = fmaf(qs[1][k], w, p1);
    p2 = fmaf(qs[2][k], w, p2);
    p3 = fmaf(qs[3][k], w, p3);
  }
  part[0][seg][c] = p0; part[1][seg][c] = p1;
  part[2][seg][c] = p2; part[3][seg][c] = p3;
  __syncthreads();
  {
    const int q = t >> 6, cc = t & 63;
    qc[q][cc] = part[q][0][cc] + part[q][1][cc] + part[q][2][cc] + part[q][3][cc];
  }
  __syncthreads();
  const int w = t >> 6, lane = t & 63;
  float g = 0.f;
  for (int j = 0; j < 64; ++j) g = fmaf(qc[w][j], G[j * 64 + lane], g);
  const int q = qb + w;
  qGT[(size_t)lane * NQ + q] = g;
  qGr[(size_t)q * DCC + lane] = g;
  qGh[(size_t)q * DCC + lane] = f2bf(g);
  float pr = qc[w][lane] * g;
  float pn = g * g;
#pragma unroll
  for (int off = 32; off; off >>= 1) {
    pr += __shfl_xor(pr, off);
    pn += __shfl_xor(pn, off);
  }
  if (lane == 0) {
    q2o[q] = pr;
    qeo[q] = EPS_A * sqrtf(pn);
  }
}

// ------- s2 = s^T G s ; sn = |s| ; ir2 = 1/(res+eps)^2 ; h = (res+eps)^2/2 ; sh bf16
__global__ __launch_bounds__(256) void s_kernel(
    const float* __restrict__ stored, const float* __restrict__ resil,
    const float* __restrict__ G, float* __restrict__ s2o,
    float* __restrict__ sno, float* __restrict__ ir2o,
    float* __restrict__ ho, unsigned short* __restrict__ sho) {
  __shared__ __align__(16) float Gl[64 * 66];
  __shared__ __align__(16) float sst[64 * 64];
  __shared__ float part2[64 * 33];
  __shared__ float ps[64 * 33];
  const int t = threadIdx.x;
  const int nb = blockIdx.x * 64;
  for (int p = 0; p < 16; ++p) {
    int i = p * 256 + t;
    Gl[(i >> 6) * 66 + (i & 63)] = G[i];
  }
  {
    const float4* src = reinterpret_cast<const float4*>(stored + (size_t)nb * DCC);
    float4* dst = reinterpret_cast<float4*>(sst);
#pragma unroll
    for (int r = 0; r < 4; ++r) dst[r * 256 + t] = src[r * 256 + t];
  }
  __syncthreads();
  const int l = t & 31, tw = t >> 5;
  float acc0[8], acc1[8];
#pragma unroll
  for (int i = 0; i < 8; ++i) { acc0[i] = 0.f; acc1[i] = 0.f; }
  for (int kb = 0; kb < 16; ++kb) {
    const float2 ga0 = *reinterpret_cast<const float2*>(&Gl[(4 * kb + 0) * 66 + 2 * l]);
    const float2 ga1 = *reinterpret_cast<const float2*>(&Gl[(4 * kb + 1) * 66 + 2 * l]);
    const float2 ga2 = *reinterpret_cast<const float2*>(&Gl[(4 * kb + 2) * 66 + 2 * l]);
    const float2 ga3 = *reinterpret_cast<const float2*>(&Gl[(4 * kb + 3) * 66 + 2 * l]);
#pragma unroll
    for (int i = 0; i < 8; ++i) {
      const float4 sv = *reinterpret_cast<const float4*>(&sst[(8 * tw + i) * 64 + 4 * kb]);
      acc0[i] = fmaf(ga3.x, sv.w, fmaf(ga2.x, sv.z, fmaf(ga1.x, sv.y, fmaf(ga0.x, sv.x, acc0[i]))));
      acc1[i] = fmaf(ga3.y, sv.w, fmaf(ga2.y, sv.z, fmaf(ga1.y, sv.y, fmaf(ga0.y, sv.x, acc1[i]))));
    }
  }
#pragma unroll
  for (int i = 0; i < 8; ++i) {
    const int n = 8 * tw + i;
    const float2 sj = *reinterpret_cast<const float2*>(&sst[n * 64 + 2 * l]);
    part2[n * 33 + l] = acc0[i] * sj.x + acc1[i] * sj.y;
    ps[n * 33 + l] = sj.x * sj.x + sj.y * sj.y;
  }
  __syncthreads();
  for (int p = 0; p < 16; ++p) {
    const int i = p * 256 + t;
    const int nl = i >> 6, k = i & 63;
    sho[(size_t)(nb + nl) * DCC + k] = f2bf(sst[nl * 64 + k]);
  }
  if (t < 64) {
    float s = 0.f, sp = 0.f;
#pragma unroll
    for (int u = 0; u < 32; ++u) { s += part2[t * 33 + u]; sp += ps[t * 33 + u]; }
    s2o[nb + t] = s;
    sno[nb + t] = sqrtf(sp);
  } else if (t < 128) {
    const int n = t - 64;
    const float rv = resil[nb + n] + EPS_RES_F;
    const float inv = 1.0f / rv;
    ir2o[nb + n] = inv * inv;
    ho[nb + n] = 0.5f * rv * rv;
  }
}

// --------- exact f32 keys for the 1/64 subsample (rows n = 64*j, j<2048)
__global__ __launch_bounds__(256) void sub_kernel(
    const float* __restrict__ stored, const float* __restrict__ qGT,
    const float* __restrict__ q2g, const float* __restrict__ s2g,
    const float* __restrict__ ir2g, float* __restrict__ skeys) {
  __shared__ __align__(16) float qg[64 * 128];
  __shared__ __align__(16) float sst[64 * 64];
  __shared__ float s2sub[64];
  __shared__ float ir2sub[64];
  const int t = threadIdx.x;
  const int jb = blockIdx.x * 64;
  const int qbase = blockIdx.y * 128;
  for (int p = 0; p < 32; ++p) {
    const int i = p * 256 + t;
    const int k = i >> 7, qq = i & 127;
    qg[k * 128 + qq] = qGT[(size_t)k * NQ + qbase + qq];
  }
#pragma unroll
  for (int p = 0; p < 4; ++p) {
    const int idx = p * 256 + t;
    const int r = idx >> 4, f4 = idx & 15;
    reinterpret_cast<float4*>(sst)[r * 16 + f4] =
        reinterpret_cast<const float4*>(stored + (size_t)(64 * (jb + r)) * DCC)[f4];
  }
  if (t < 64) s2sub[t] = s2g[64 * (jb + t)];
  else if (t < 128) ir2sub[t - 64] = ir2g[64 * (jb + t - 64)];
  __syncthreads();
  const int l = t & 31, tw = t >> 5;
  const int q0 = 4 * l;
  float q2r[4];
#pragma unroll
  for (int qq = 0; qq < 4; ++qq) q2r[qq] = q2g[qbase + q0 + qq];
  float acc[4][8];
#pragma unroll
  for (int qq = 0; qq < 4; ++qq)
#pragma unroll
    for (int i = 0; i < 8; ++i) acc[qq][i] = 0.f;
  for (int kb = 0; kb < 16; ++kb) {
    const float4 qa0 = *reinterpret_cast<const float4*>(&qg[(4 * kb + 0) * 128 + q0]);
    const float4 qa1 = *reinterpret_cast<const float4*>(&qg[(4 * kb + 1) * 128 + q0]);
    const float4 qa2 = *reinterpret_cast<const float4*>(&qg[(4 * kb + 2) * 128 + q0]);
    const float4 qa3 = *reinterpret_cast<const float4*>(&qg[(4 * kb + 3) * 128 + q0]);
#pragma unroll
    for (int i = 0; i < 8; ++i) {
      const float4 sv = *reinterpret_cast<const float4*>(&sst[(8 * tw + i) * 64 + 4 * kb]);
      acc[0][i] = fmaf(qa3.x, sv.w, fmaf(qa2.x, sv.z, fmaf(qa1.x, sv.y, fmaf(qa0.x, sv.x, acc[0][i]))));
      acc[1][i] = fmaf(qa3.y, sv.w, fmaf(qa2.y, sv.z, fmaf(qa1.y, sv.y, fmaf(qa0.y, sv.x, acc[1][i]))));
      acc[2][i] = fmaf(qa3.z, sv.w, fmaf(qa2.z, sv.z, fmaf(qa1.z, sv.y, fmaf(qa0.z, sv.x, acc[2][i]))));
      acc[3][i] = fmaf(qa3.w, sv.w, fmaf(qa2.w, sv.z, fmaf(qa1.w, sv.y, fmaf(qa0.w, sv.x, acc[3][i]))));
    }
  }
#pragma unroll
  for (int i = 0; i < 8; ++i) {
    const int jl = 8 * tw + i;
    const float s2v = s2sub[jl];
    const float ir2v = ir2sub[jl];
#pragma unroll
    for (int qq = 0; qq < 4; ++qq) {
      const float d2 = fmaf(-2.f, acc[qq][i], q2r[qq] + s2v);
      const float key = (fmaxf(d2, 0.f) + EPS_SQRT_F) * ir2v;
      skeys[(size_t)(qbase + q0 + qq) * 2048 + jb + jl] = key;
    }
  }
}

// ---- tau[q] = 16th smallest subsample key (exact), *1.0001 margin
// 256 threads: per-thread sorted top-16 -> per-wave shfl merge -> cross-wave merge
__global__ __launch_bounds__(256) void tau_select(
    const float* __restrict__ skeys, float* __restrict__ tau) {
  __shared__ float lk[256 * 17];
  __shared__ float wkv[4][16];
  const int t = threadIdx.x;
  const int lane = t & 63, w = t >> 6;
  const int q = blockIdx.x;
  float k16[16];
#pragma unroll
  for (int s = 0; s < 16; ++s) k16[s] = 3.0e38f;
  for (int i = t; i < 2048; i += 256) {
    const float key = skeys[(size_t)q * 2048 + i];
    if (key < k16[15]) {
#pragma unroll
      for (int s = 15; s >= 1; --s) {
        const bool dprev = key < k16[s - 1];
        const float nk = dprev ? k16[s - 1] : key;
        if (key < k16[s]) k16[s] = nk;
      }
      if (key < k16[0]) k16[0] = key;
    }
  }
#pragma unroll
  for (int s = 0; s < 16; ++s) lk[t * 17 + s] = k16[s];
  __syncthreads();
  {
    int ptr = 0;
    for (int r = 0; r < K_TOP; ++r) {
      float v = lk[t * 17 + ptr];
      int who = lane;
#pragma unroll
      for (int off = 32; off; off >>= 1) {
        const float ov = __shfl_xor(v, off);
        const int ow = __shfl_xor(who, off);
        if (ov < v || (ov == v && ow < who)) { v = ov; who = ow; }
      }
      if (lane == 0) wkv[w][r] = v;
      if (lane == who) ptr++;
    }
  }
  __syncthreads();
  if (w == 0) {
    float v = wkv[lane >> 4][lane & 15];
    float t16 = 0.f;
    for (int r = 0; r < K_TOP; ++r) {
      float mv = v;
      int who = lane;
#pragma unroll
      for (int off = 32; off; off >>= 1) {
        const float ov = __shfl_xor(mv, off);
        const int ow = __shfl_xor(who, off);
        if (ov < mv || (ov == mv && ow < who)) { mv = ov; who = ow; }
      }
      t16 = mv;
      if (lane == who) v = 3.0e38f;
    }
    if (lane == 0) tau[q] = t16 * 1.0001f;
  }
}

// --------------- MFMA screening pass: bf16-hi cross-GEMM + bounded filter
// accept iff  a >= q2/2 + s2/2 - tau*h - (EPS_A*|qG|)*|s|   (provable superset)
// accepts recorded as row indices in block-owned segments; LDS counters only.
__global__ __launch_bounds__(256, 2) void main_mfma(
    const unsigned short* __restrict__ sh, const unsigned short* __restrict__ qGh,
    const float* __restrict__ q2g, const float* __restrict__ qeg,
    const float* __restrict__ taug, const float* __restrict__ s2g,
    const float* __restrict__ hg, const float* __restrict__ sng,
    int* __restrict__ ccnt, int* __restrict__ ovcnt,
    unsigned int* __restrict__ ovf, unsigned int* __restrict__ candIdx,
    int slots) {
  __shared__ __align__(16) char smA[32768];  // 256 n-rows x 128B bf16, XOR-swizzled
  __shared__ __align__(16) char smB[16384];  // 128 q-rows x 128B bf16, XOR-swizzled
  __shared__ float s2t[256], ht[256], snt[256];
  __shared__ int cnt128[128];
  const int t = threadIdx.x;
  const int lane = t & 63, w = t >> 6;
  const int l15 = lane & 15, hi4 = (lane >> 4) << 2;
  const int chunk = blockIdx.x;   // 0..63 (linear%8 == chunk%8 -> XCD pinned)
  const int qbase = blockIdx.y * 128;
  const int sx = ((lane & 7) << 4) ^ ((lane >> 3) << 4);
  const int g16 = (lane >> 4) << 4, swz = (lane & 7) << 4;
  const int kx0 = g16 ^ swz;
  const int kx1 = (64 | g16) ^ swz;

  if (t < 128) cnt128[t] = 0;
#pragma unroll
  for (int ii = 0; ii < 4; ++ii) {
    const int row = w * 32 + ii * 8 + (lane >> 3);
    gl_lds16((const char*)qGh + (size_t)(qbase + row) * 128 + sx,
             smB + w * 4096 + ii * 1024);
  }
  float q2h_r[8], tau_r[8], qe_r[8];
#pragma unroll
  for (int qi = 0; qi < 8; ++qi) {
    const int q = qbase + qi * 16 + l15;
    q2h_r[qi] = 0.5f * q2g[q];
    tau_r[qi] = taug[q];
    qe_r[qi] = qeg[q];
  }
  const f32x4 z4 = {0.f, 0.f, 0.f, 0.f};

  for (int nt = 0; nt < 8; ++nt) {
    const int nb = chunk * 2048 + nt * 256;
    __syncthreads();
#pragma unroll
    for (int ii = 0; ii < 8; ++ii) {
      const int row = w * 64 + ii * 8 + (lane >> 3);
      gl_lds16((const char*)sh + (size_t)(nb + row) * 128 + sx,
               smA + w * 8192 + ii * 1024);
    }
    s2t[t] = s2g[nb + t];
    ht[t] = hg[nb + t];
    snt[t] = sng[nb + t];
    __syncthreads();

    f32x4 acc[4][8];
    {
      short8v bfr[8];
#pragma unroll
      for (int qi = 0; qi < 8; ++qi)
        bfr[qi] = *reinterpret_cast<const short8v*>(smB + ((qi * 16 + l15) << 7) + kx0);
#pragma unroll
      for (int ni = 0; ni < 4; ++ni) {
        const short8v af = *reinterpret_cast<const short8v*>(
            smA + ((w * 64 + ni * 16 + l15) << 7) + kx0);
#pragma unroll
        for (int qi = 0; qi < 8; ++qi)
          acc[ni][qi] = __builtin_amdgcn_mfma_f32_16x16x32_bf16(af, bfr[qi], z4, 0, 0, 0);
      }
#pragma unroll
      for (int qi = 0; qi < 8; ++qi)
        bfr[qi] = *reinterpret_cast<const short8v*>(smB + ((qi * 16 + l15) << 7) + kx1);
#pragma unroll
      for (int ni = 0; ni < 4; ++ni) {
        const short8v af = *reinterpret_cast<const short8v*>(
            smA + ((w * 64 + ni * 16 + l15) << 7) + kx1);
#pragma unroll
        for (int qi = 0; qi < 8; ++qi)
          acc[ni][qi] = __builtin_amdgcn_mfma_f32_16x16x32_bf16(af, bfr[qi], acc[ni][qi], 0, 0, 0);
      }
    }
    // epilogue: C/D map col(q)=lane&15, row(n)=(lane>>4)*4+reg
#pragma unroll
    for (int ni = 0; ni < 4; ++ni) {
#pragma unroll
      for (int r = 0; r < 4; ++r) {
        const int nl = w * 64 + ni * 16 + hi4 + r;
        const float s2n = s2t[nl], hn = ht[nl], snn = snt[nl];
#pragma unroll
        for (int qi = 0; qi < 8; ++qi) {
          const float a = acc[ni][qi][r];
          const float t1 = fmaf(0.5f, s2n, q2h_r[qi]);
          const float thr = fmaf(-qe_r[qi], snn, fmaf(-tau_r[qi], hn, t1));
          if (a >= thr) {
            const int ql = qi * 16 + l15;
            const int n = nb + nl;
            const int pos = atomicAdd(&cnt128[ql], 1);   // LDS atomic (fast)
            if (pos < slots) {
              candIdx[((size_t)((qbase + ql) * 64 + chunk)) * slots + pos] = (unsigned)n;
            } else {
              const int gp = atomicAdd(ovcnt, 1);        // global, ~never
              if (gp < OVCAP) ovf[gp] = ((unsigned)(qbase + ql) << 17) | (unsigned)n;
            }
          }
        }
      }
    }
  }
  __syncthreads();
  if (t < 128) {
    int c = cnt128[t];
    if (c > slots) c = slots;
    ccnt[(size_t)(qbase + t) * 64 + chunk] = c;
  }
}

// ------ final: exact f32 refine of EVERY candidate, lexicographic top-16
// 256 threads / q: flattened candidate space, full-lane strided processing.
__global__ __launch_bounds__(256) void final_kernel(
    const unsigned int* __restrict__ candIdx, const int* __restrict__ ccnt,
    const int* __restrict__ ovcnt, const unsigned int* __restrict__ ovf,
    const float* __restrict__ qGr, const float* __restrict__ q2g,
    const float* __restrict__ stored, const float* __restrict__ s2g,
    const float* __restrict__ ir2g, float* __restrict__ out, int slots) {
  __shared__ __align__(16) float qgl[64];
  __shared__ int ccl[64];
  __shared__ int offs[64];
  __shared__ unsigned short cid[MCAP];
  __shared__ int mtot;
  __shared__ float wkv[4][16];
  __shared__ int wiv[4][16];
  __shared__ float lk[256 * 17];
  __shared__ int li[256 * 17];
  const int t = threadIdx.x;
  const int lane = t & 63, w = t >> 6;
  const int q = blockIdx.x;
  if (t < 64) {
    qgl[t] = qGr[(size_t)q * DCC + t];
    ccl[t] = min(ccnt[(size_t)q * 64 + t], slots);
  }
  __syncthreads();
  if (w == 0) {  // exclusive prefix over 64 counts (shfl scan)
    int c = ccl[lane];
    int inc = c;
#pragma unroll
    for (int off = 1; off < 64; off <<= 1) {
      const int u = __shfl_up(inc, off);
      if (lane >= off) inc += u;
    }
    offs[lane] = inc - c;
    if (lane == 63) mtot = inc;
  }
  __syncthreads();
  const int m = mtot;  // m <= 64*slots <= MCAP always
  // build flattened chunk-id map
  if (t < 64) {
    const int base = offs[t], c = ccl[t];
    for (int j = 0; j < c; ++j) cid[base + j] = (unsigned short)t;
  }
  __syncthreads();
  const float q2v = q2g[q];
  float k16[16];
  int i16[16];
#pragma unroll
  for (int s = 0; s < 16; ++s) { k16[s] = 3.0e38f; i16[s] = 0x7FFFFFFF; }
  for (int i = t; i < m; i += 256) {
    const int k = cid[i];
    const int j = i - offs[k];
    const int n = (int)candIdx[((size_t)(q * 64 + k)) * slots + j];
    const float key = exact_key(stored, qgl, q2v, s2g, ir2g, n);
    ins16(key, n, k16, i16);
  }
  {  // overflow list (normally empty)
    int oc = *ovcnt;
    if (oc > OVCAP) oc = OVCAP;
    for (int i = t; i < oc; i += 256) {
      const unsigned pk = ovf[i];
      if ((int)(pk >> 17) == q) {
        const int n = (int)(pk & 0x1FFFFu);
        const float key = exact_key(stored, qgl, q2v, s2g, ir2g, n);
        ins16(key, n, k16, i16);
      }
    }
  }
#pragma unroll
  for (int s = 0; s < 16; ++s) { lk[t * 17 + s] = k16[s]; li[t * 17 + s] = i16[s]; }
  __syncthreads();
  {  // per-wave merge of 64 sorted lists -> wave top-16
    int ptr = 0;
    for (int r = 0; r < K_TOP; ++r) {
      float v = lk[t * 17 + ptr];
      int id = li[t * 17 + ptr];
      int who = lane;
#pragma unroll
      for (int off = 32; off; off >>= 1) {
        const float ov = __shfl_xor(v, off);
        const int oid = __shfl_xor(id, off);
        const int ow = __shfl_xor(who, off);
        if (ov < v || (ov == v && oid < id)) { v = ov; id = oid; who = ow; }
      }
      if (lane == 0) { wkv[w][r] = v; wiv[w][r] = id; }
      if (lane == who) ptr++;
    }
  }
  __syncthreads();
  if (w == 0) {  // cross-wave merge: 64 entries (4 waves x 16), repeated extract-min
    float v = wkv[lane >> 4][lane & 15];
    int id = wiv[lane >> 4][lane & 15];
    for (int r = 0; r < K_TOP; ++r) {
      float mv = v;
      int mid = id;
      int who = lane;
#pragma unroll
      for (int off = 32; off; off >>= 1) {
        const float ov = __shfl_xor(mv, off);
        const int oid = __shfl_xor(mid, off);
        const int ow = __shfl_xor(who, off);
        if (ov < mv || (ov == mv && oid < mid)) { mv = ov; mid = oid; who = ow; }
      }
      if (lane == 0) {
        out[q * K_TOP + r] = sqrtf(mv);
        out[NQ * K_TOP + q * K_TOP + r] = (float)mid;
      }
      if (lane == who) { v = 3.0e38f; id = 0x7FFFFFFF; }
    }
  }
}

// ----------------------------------------------------------------- launcher
extern "C" void kernel_launch(void* const* d_in, const int* in_sizes, int n_in,
                              void* d_out, int out_size, void* d_ws, size_t ws_size,
                              hipStream_t stream) {
  const float* query  = (const float*)d_in[0];
  const float* stored = (const float*)d_in[1];
  const float* resil  = (const float*)d_in[2];
  const float* W      = (const float*)d_in[3];
  const float* M      = (const float*)d_in[4];

  char* ws = (char*)d_ws;
  size_t off = 0;
  float* G    = (float*)(ws + off); off += 16384;
  float* qGT  = (float*)(ws + off); off += 262144;   // [64][1024] f32
  float* qGr  = (float*)(ws + off); off += 262144;   // [1024][64] f32
  unsigned short* qGh = (unsigned short*)(ws + off); off += 131072;  // bf16
  float* q2   = (float*)(ws + off); off += 4096;
  float* qe   = (float*)(ws + off); off += 4096;
  float* tau  = (float*)(ws + off); off += 4096;
  float* s2   = (float*)(ws + off); off += 524288;
  float* h    = (float*)(ws + off); off += 524288;
  float* sn   = (float*)(ws + off); off += 524288;
  float* ir2  = (float*)(ws + off); off += 524288;
  int*   ccnt = (int*)(ws + off);   off += 262144;   // [1024][64]
  int*   ovcnt = (int*)(ws + off);  off += 4096;
  unsigned int* ovf = (unsigned int*)(ws + off); off += 32768;  // 8192 entries
  unsigned short* sh = (unsigned short*)(ws + off); off += 16777216;  // bf16 rows
  unsigned int* candIdx = (unsigned int*)(ws + off);  // [1024][64][slots] u32
  float* skeys = (float*)candIdx;  // overlay (8 MB, used before candIdx)

  int slots = 64;
  if (ws_size < off + (size_t)NQ * 64 * 64 * 4) slots = 32;

  float* out = (float*)d_out;

  hipMemsetAsync(ovcnt, 0, 4096, stream);
  g_kernel<<<16, 256, 0, stream>>>(M, G);
  q_kernel<<<NQ / 4, 256, 0, stream>>>(query, W, G, qGT, qGr, qGh, q2, qe);
  s_kernel<<<NS / 64, 256, 0, stream>>>(stored, resil, G, s2, sn, ir2, h, sh);
  sub_kernel<<<dim3(32, 8), 256, 0, stream>>>(stored, qGT, q2, s2, ir2, skeys);
  tau_select<<<NQ, 256, 0, stream>>>(skeys, tau);
  main_mfma<<<dim3(64, 8), 256, 0, stream>>>(sh, qGh, q2, qe, tau, s2, h, sn,
                                             ccnt, ovcnt, ovf, candIdx, slots);
  final_kernel<<<NQ, 256, 0, stream>>>(candIdx, ccnt, ovcnt, ovf, qGr, q2,
                                       stored, s2, ir2, out, slots);
}

// Round 5
// 303.417 us; speedup vs baseline: 1.7926x; 1.0059x over previous
//
#include <hip/hip_runtime.h>
#include <stdint.h>

// Problem constants (fixed by the reference)
#define NQ 1024
#define NS 131072
#define DMM 2048
#define DCC 64
#define K_TOP 16
#define EPS_RES_F 1e-8f
#define EPS_SQRT_F 1e-12f
#define EPS_A 0.01f       // bf16 hi-only dot abs-error coeff (rigorous bound ~0.004)

#define OVCAP 65536       // global overflow list capacity (normally unused)
#define MCAP 2816         // max candidates per query = 64 chunks * 44 slots
#define SCAP 1024         // survivor capacity (expected ~30)

typedef __attribute__((ext_vector_type(8))) short short8v;  // 8 x bf16
typedef __attribute__((ext_vector_type(4))) float f32x4;

__device__ __forceinline__ unsigned short f2bf(float x) {  // RNE f32->bf16
  unsigned u = __float_as_uint(x);
  unsigned r = (u + 0x7FFFu + ((u >> 16) & 1u)) >> 16;
  return (unsigned short)r;
}
// directed bf16 rounding for POSITIVE floats (bounds stay provable)
__device__ __forceinline__ unsigned bf16_down_pos(float x) {
  return __float_as_uint(x) >> 16;
}
__device__ __forceinline__ unsigned bf16_up_pos(float x) {
  const unsigned u = __float_as_uint(x);
  return (u >> 16) + ((u & 0xFFFFu) ? 1u : 0u);
}

__device__ __forceinline__ void gl_lds16(const void* g, void* l) {
  __builtin_amdgcn_global_load_lds(
      (const __attribute__((address_space(1))) unsigned int*)g,
      (__attribute__((address_space(3))) unsigned int*)l, 16, 0, 0);
}

__device__ __forceinline__ bool lex_lt(float ka, int ia, float kb, int ib) {
  return (ka < kb) || (ka == kb && ia < ib);
}

__device__ __forceinline__ void ins16(float key, int idx, float (&k16)[16], int (&i16)[16]) {
  if (lex_lt(key, idx, k16[15], i16[15])) {
#pragma unroll
    for (int s = 15; s >= 1; --s) {
      const bool dprev = lex_lt(key, idx, k16[s - 1], i16[s - 1]);
      const bool dcur = lex_lt(key, idx, k16[s], i16[s]);
      const float nk = dprev ? k16[s - 1] : key;
      const int ni = dprev ? i16[s - 1] : idx;
      if (dcur) { k16[s] = nk; i16[s] = ni; }
    }
    if (lex_lt(key, idx, k16[0], i16[0])) { k16[0] = key; i16[0] = idx; }
  }
}

// exact key chain — MUST stay bit-identical to sub_kernel's accumulation
__device__ __forceinline__ float exact_key(const float* __restrict__ stored,
                                           const float* qgl, float q2v,
                                           const float* __restrict__ s2g,
                                           const float* __restrict__ ir2g, int n) {
  const float4* srow = reinterpret_cast<const float4*>(stored + (size_t)n * DCC);
  float a = 0.f;
#pragma unroll
  for (int kb = 0; kb < 16; ++kb) {
    const float4 qv = *reinterpret_cast<const float4*>(&qgl[4 * kb]);
    const float4 sv = srow[kb];
    a = fmaf(qv.w, sv.w, fmaf(qv.z, sv.z, fmaf(qv.y, sv.y, fmaf(qv.x, sv.x, a))));
  }
  const float d2 = fmaf(-2.f, a, q2v + s2g[n]);
  return (fmaxf(d2, 0.f) + EPS_SQRT_F) * ir2g[n];
}

// wave-level merge: each lane holds ascending k16/i16; lane0 writes wave top-16
__device__ __forceinline__ void wave_extract16(float (&k16)[16], int (&i16)[16],
                                               int lane, float* ok, int* oi) {
  for (int r = 0; r < K_TOP; ++r) {
    float v = k16[0];
    int id = i16[0];
    int who = lane;
#pragma unroll
    for (int off = 32; off; off >>= 1) {
      const float ov = __shfl_xor(v, off);
      const int oid = __shfl_xor(id, off);
      const int ow = __shfl_xor(who, off);
      if (ov < v || (ov == v && oid < id)) { v = ov; id = oid; who = ow; }
    }
    if (lane == 0) { ok[r] = v; oi[r] = id; }
    if (lane == who) {
#pragma unroll
      for (int s = 0; s < 15; ++s) { k16[s] = k16[s + 1]; i16[s] = i16[s + 1]; }
      k16[15] = 3.0e38f;
      i16[15] = 0x7FFFFFFF;
    }
  }
}

// ---------------------------------------------------------------- G = M M^T
__global__ __launch_bounds__(256) void g_kernel(const float* __restrict__ M,
                                                float* __restrict__ G) {
  __shared__ __align__(16) float Ml[64 * 66];
  const int t = threadIdx.x;
  for (int p = 0; p < 16; ++p) {
    int i = p * 256 + t;
    Ml[(i >> 6) * 66 + (i & 63)] = M[i];
  }
  __syncthreads();
  const int e = blockIdx.x * 256 + t;
  const int i = e >> 6, j = e & 63;
  float a = 0.f;
#pragma unroll
  for (int k = 0; k < 64; ++k) a = fmaf(Ml[i * 66 + k], Ml[j * 66 + k], a);
  G[e] = a;
}

// ---------------- qc = q W ; qG = qc G ; q2 = qc.qG ; qGh bf16 ; qe = eps*|qG|
__global__ __launch_bounds__(256) void q_kernel(
    const float* __restrict__ query, const float* __restrict__ W,
    const float* __restrict__ G, float* __restrict__ qGT,
    float* __restrict__ qGr, unsigned short* __restrict__ qGh,
    float* __restrict__ q2o, float* __restrict__ qeo) {
  __shared__ __align__(16) float qs[4][DMM];
  __shared__ float part[4][4][64];
  __shared__ float qc[4][64];
  const int t = threadIdx.x;
  const int qb = blockIdx.x * 4;
  {
    const float4* src = reinterpret_cast<const float4*>(query + (size_t)qb * DMM);
    float4* dst = reinterpret_cast<float4*>(&qs[0][0]);
#pragma unroll
    for (int r = 0; r < 8; ++r) dst[r * 256 + t] = src[r * 256 + t];
  }
  __syncthreads();
  const int c = t & 63, seg = t >> 6;
  float p0 = 0.f, p1 = 0.f, p2 = 0.f, p3 = 0.f;
  const int kbase = seg * 512;
  for (int ki = 0; ki < 512; ++ki) {
    const int k = kbase + ki;
    const float w = W[(size_t)k * 64 + c];
    p0 = fmaf(qs[0][k], w, p0);
    p1 = fmaf(qs[1][k], w, p1);
    p2 = fmaf(qs[2][k], w, p2);
    p3 = fmaf(qs[3][k], w, p3);
  }
  part[0][seg][c] = p0; part[1][seg][c] = p1;
  part[2][seg][c] = p2; part[3][seg][c] = p3;
  __syncthreads();
  {
    const int q = t >> 6, cc = t & 63;
    qc[q][cc] = part[q][0][cc] + part[q][1][cc] + part[q][2][cc] + part[q][3][cc];
  }
  __syncthreads();
  const int w = t >> 6, lane = t & 63;
  float g = 0.f;
  for (int j = 0; j < 64; ++j) g = fmaf(qc[w][j], G[j * 64 + lane], g);
  const int q = qb + w;
  qGT[(size_t)lane * NQ + q] = g;
  qGr[(size_t)q * DCC + lane] = g;
  qGh[(size_t)q * DCC + lane] = f2bf(g);
  float pr = qc[w][lane] * g;
  float pn = g * g;
#pragma unroll
  for (int off = 32; off; off >>= 1) {
    pr += __shfl_xor(pr, off);
    pn += __shfl_xor(pn, off);
  }
  if (lane == 0) {
    q2o[q] = pr;
    qeo[q] = EPS_A * sqrtf(pn);
  }
}

// ------- s2 = s^T G s ; sn = |s| ; ir2 = 1/(res+eps)^2 ; h = (res+eps)^2/2 ; sh bf16
__global__ __launch_bounds__(256) void s_kernel(
    const float* __restrict__ stored, const float* __restrict__ resil,
    const float* __restrict__ G, float* __restrict__ s2o,
    float* __restrict__ sno, float* __restrict__ ir2o,
    float* __restrict__ ho, unsigned short* __restrict__ sho) {
  __shared__ __align__(16) float Gl[64 * 66];
  __shared__ __align__(16) float sst[64 * 64];
  __shared__ float part2[64 * 33];
  __shared__ float ps[64 * 33];
  const int t = threadIdx.x;
  const int nb = blockIdx.x * 64;
  for (int p = 0; p < 16; ++p) {
    int i = p * 256 + t;
    Gl[(i >> 6) * 66 + (i & 63)] = G[i];
  }
  {
    const float4* src = reinterpret_cast<const float4*>(stored + (size_t)nb * DCC);
    float4* dst = reinterpret_cast<float4*>(sst);
#pragma unroll
    for (int r = 0; r < 4; ++r) dst[r * 256 + t] = src[r * 256 + t];
  }
  __syncthreads();
  const int l = t & 31, tw = t >> 5;
  float acc0[8], acc1[8];
#pragma unroll
  for (int i = 0; i < 8; ++i) { acc0[i] = 0.f; acc1[i] = 0.f; }
  for (int kb = 0; kb < 16; ++kb) {
    const float2 ga0 = *reinterpret_cast<const float2*>(&Gl[(4 * kb + 0) * 66 + 2 * l]);
    const float2 ga1 = *reinterpret_cast<const float2*>(&Gl[(4 * kb + 1) * 66 + 2 * l]);
    const float2 ga2 = *reinterpret_cast<const float2*>(&Gl[(4 * kb + 2) * 66 + 2 * l]);
    const float2 ga3 = *reinterpret_cast<const float2*>(&Gl[(4 * kb + 3) * 66 + 2 * l]);
#pragma unroll
    for (int i = 0; i < 8; ++i) {
      const float4 sv = *reinterpret_cast<const float4*>(&sst[(8 * tw + i) * 64 + 4 * kb]);
      acc0[i] = fmaf(ga3.x, sv.w, fmaf(ga2.x, sv.z, fmaf(ga1.x, sv.y, fmaf(ga0.x, sv.x, acc0[i]))));
      acc1[i] = fmaf(ga3.y, sv.w, fmaf(ga2.y, sv.z, fmaf(ga1.y, sv.y, fmaf(ga0.y, sv.x, acc1[i]))));
    }
  }
#pragma unroll
  for (int i = 0; i < 8; ++i) {
    const int n = 8 * tw + i;
    const float2 sj = *reinterpret_cast<const float2*>(&sst[n * 64 + 2 * l]);
    part2[n * 33 + l] = acc0[i] * sj.x + acc1[i] * sj.y;
    ps[n * 33 + l] = sj.x * sj.x + sj.y * sj.y;
  }
  __syncthreads();
  for (int p = 0; p < 16; ++p) {
    const int i = p * 256 + t;
    const int nl = i >> 6, k = i & 63;
    sho[(size_t)(nb + nl) * DCC + k] = f2bf(sst[nl * 64 + k]);
  }
  if (t < 64) {
    float s = 0.f, sp = 0.f;
#pragma unroll
    for (int u = 0; u < 32; ++u) { s += part2[t * 33 + u]; sp += ps[t * 33 + u]; }
    s2o[nb + t] = s;
    sno[nb + t] = sqrtf(sp);
  } else if (t < 128) {
    const int n = t - 64;
    const float rv = resil[nb + n] + EPS_RES_F;
    const float inv = 1.0f / rv;
    ir2o[nb + n] = inv * inv;
    ho[nb + n] = 0.5f * rv * rv;
  }
}

// --------- exact f32 keys for the 1/64 subsample (rows n = 64*j, j<2048)
__global__ __launch_bounds__(256) void sub_kernel(
    const float* __restrict__ stored, const float* __restrict__ qGT,
    const float* __restrict__ q2g, const float* __restrict__ s2g,
    const float* __restrict__ ir2g, float* __restrict__ skeys) {
  __shared__ __align__(16) float qg[64 * 128];
  __shared__ __align__(16) float sst[64 * 64];
  __shared__ float s2sub[64];
  __shared__ float ir2sub[64];
  const int t = threadIdx.x;
  const int jb = blockIdx.x * 64;
  const int qbase = blockIdx.y * 128;
  for (int p = 0; p < 32; ++p) {
    const int i = p * 256 + t;
    const int k = i >> 7, qq = i & 127;
    qg[k * 128 + qq] = qGT[(size_t)k * NQ + qbase + qq];
  }
#pragma unroll
  for (int p = 0; p < 4; ++p) {
    const int idx = p * 256 + t;
    const int r = idx >> 4, f4 = idx & 15;
    reinterpret_cast<float4*>(sst)[r * 16 + f4] =
        reinterpret_cast<const float4*>(stored + (size_t)(64 * (jb + r)) * DCC)[f4];
  }
  if (t < 64) s2sub[t] = s2g[64 * (jb + t)];
  else if (t < 128) ir2sub[t - 64] = ir2g[64 * (jb + t - 64)];
  __syncthreads();
  const int l = t & 31, tw = t >> 5;
  const int q0 = 4 * l;
  float q2r[4];
#pragma unroll
  for (int qq = 0; qq < 4; ++qq) q2r[qq] = q2g[qbase + q0 + qq];
  float acc[4][8];
#pragma unroll
  for (int qq = 0; qq < 4; ++qq)
#pragma unroll
    for (int i = 0; i < 8; ++i) acc[qq][i] = 0.f;
  for (int kb = 0; kb < 16; ++kb) {
    const float4 qa0 = *reinterpret_cast<const float4*>(&qg[(4 * kb + 0) * 128 + q0]);
    const float4 qa1 = *reinterpret_cast<const float4*>(&qg[(4 * kb + 1) * 128 + q0]);
    const float4 qa2 = *reinterpret_cast<const float4*>(&qg[(4 * kb + 2) * 128 + q0]);
    const float4 qa3 = *reinterpret_cast<const float4*>(&qg[(4 * kb + 3) * 128 + q0]);
#pragma unroll
    for (int i = 0; i < 8; ++i) {
      const float4 sv = *reinterpret_cast<const float4*>(&sst[(8 * tw + i) * 64 + 4 * kb]);
      acc[0][i] = fmaf(qa3.x, sv.w, fmaf(qa2.x, sv.z, fmaf(qa1.x, sv.y, fmaf(qa0.x, sv.x, acc[0][i]))));
      acc[1][i] = fmaf(qa3.y, sv.w, fmaf(qa2.y, sv.z, fmaf(qa1.y, sv.y, fmaf(qa0.y, sv.x, acc[1][i]))));
      acc[2][i] = fmaf(qa3.z, sv.w, fmaf(qa2.z, sv.z, fmaf(qa1.z, sv.y, fmaf(qa0.z, sv.x, acc[2][i]))));
      acc[3][i] = fmaf(qa3.w, sv.w, fmaf(qa2.w, sv.z, fmaf(qa1.w, sv.y, fmaf(qa0.w, sv.x, acc[3][i]))));
    }
  }
#pragma unroll
  for (int i = 0; i < 8; ++i) {
    const int jl = 8 * tw + i;
    const float s2v = s2sub[jl];
    const float ir2v = ir2sub[jl];
#pragma unroll
    for (int qq = 0; qq < 4; ++qq) {
      const float d2 = fmaf(-2.f, acc[qq][i], q2r[qq] + s2v);
      const float key = (fmaxf(d2, 0.f) + EPS_SQRT_F) * ir2v;
      skeys[(size_t)(qbase + q0 + qq) * 2048 + jb + jl] = key;
    }
  }
}

// ---- tau[q] = 16th smallest subsample key (exact), *1.0001 margin
__global__ __launch_bounds__(256) void tau_select(
    const float* __restrict__ skeys, float* __restrict__ tau) {
  __shared__ float lk[256 * 17];
  __shared__ float wkv[4][16];
  const int t = threadIdx.x;
  const int lane = t & 63, w = t >> 6;
  const int q = blockIdx.x;
  float k16[16];
#pragma unroll
  for (int s = 0; s < 16; ++s) k16[s] = 3.0e38f;
  for (int i = t; i < 2048; i += 256) {
    const float key = skeys[(size_t)q * 2048 + i];
    if (key < k16[15]) {
#pragma unroll
      for (int s = 15; s >= 1; --s) {
        const bool dprev = key < k16[s - 1];
        const float nk = dprev ? k16[s - 1] : key;
        if (key < k16[s]) k16[s] = nk;
      }
      if (key < k16[0]) k16[0] = key;
    }
  }
#pragma unroll
  for (int s = 0; s < 16; ++s) lk[t * 17 + s] = k16[s];
  __syncthreads();
  {
    int ptr = 0;
    for (int r = 0; r < K_TOP; ++r) {
      float v = lk[t * 17 + ptr];
      int who = lane;
#pragma unroll
      for (int off = 32; off; off >>= 1) {
        const float ov = __shfl_xor(v, off);
        const int ow = __shfl_xor(who, off);
        if (ov < v || (ov == v && ow < who)) { v = ov; who = ow; }
      }
      if (lane == 0) wkv[w][r] = v;
      if (lane == who) ptr++;
    }
  }
  __syncthreads();
  if (w == 0) {
    float v = wkv[lane >> 4][lane & 15];
    float t16 = 0.f;
    for (int r = 0; r < K_TOP; ++r) {
      float mv = v;
      int who = lane;
#pragma unroll
      for (int off = 32; off; off >>= 1) {
        const float ov = __shfl_xor(mv, off);
        const int ow = __shfl_xor(who, off);
        if (ov < mv || (ov == mv && ow < who)) { mv = ov; who = ow; }
      }
      t16 = mv;
      if (lane == who) v = 3.0e38f;
    }
    if (lane == 0) tau[q] = t16 * 1.0001f;
  }
}

// --------------- MFMA screening pass: bf16-hi cross-GEMM + bounded filter
// accept iff  a >= q2/2 + s2/2 - tau*h - (EPS_A*|qG|)*|s|   (provable superset)
// stores u64: [63:48] bf16-UP upper key, [47:32] bf16-DOWN lower key, [31:0] n
__global__ __launch_bounds__(256, 2) void main_mfma(
    const unsigned short* __restrict__ sh, const unsigned short* __restrict__ qGh,
    const float* __restrict__ q2g, const float* __restrict__ qeg,
    const float* __restrict__ taug, const float* __restrict__ s2g,
    const float* __restrict__ hg, const float* __restrict__ sng,
    const float* __restrict__ ir2g, int* __restrict__ ccnt,
    int* __restrict__ ovcnt, unsigned int* __restrict__ ovf,
    unsigned long long* __restrict__ cand, int slots) {
  __shared__ __align__(16) char smA[32768];  // 256 n-rows x 128B bf16, XOR-swizzled
  __shared__ __align__(16) char smB[16384];  // 128 q-rows x 128B bf16, XOR-swizzled
  __shared__ float s2t[256], ht[256], snt[256], ir2t[256];
  __shared__ int cnt128[128];
  const int t = threadIdx.x;
  const int lane = t & 63, w = t >> 6;
  const int l15 = lane & 15, hi4 = (lane >> 4) << 2;
  const int chunk = blockIdx.x;   // 0..63 (linear%8 == chunk%8 -> XCD pinned)
  const int qbase = blockIdx.y * 128;
  const int sx = ((lane & 7) << 4) ^ ((lane >> 3) << 4);
  const int g16 = (lane >> 4) << 4, swz = (lane & 7) << 4;
  const int kx0 = g16 ^ swz;
  const int kx1 = (64 | g16) ^ swz;

  if (t < 128) cnt128[t] = 0;
#pragma unroll
  for (int ii = 0; ii < 4; ++ii) {
    const int row = w * 32 + ii * 8 + (lane >> 3);
    gl_lds16((const char*)qGh + (size_t)(qbase + row) * 128 + sx,
             smB + w * 4096 + ii * 1024);
  }
  float q2h_r[8], tau_r[8], qe_r[8];
#pragma unroll
  for (int qi = 0; qi < 8; ++qi) {
    const int q = qbase + qi * 16 + l15;
    q2h_r[qi] = 0.5f * q2g[q];
    tau_r[qi] = taug[q];
    qe_r[qi] = qeg[q];
  }
  const f32x4 z4 = {0.f, 0.f, 0.f, 0.f};

  for (int nt = 0; nt < 8; ++nt) {
    const int nb = chunk * 2048 + nt * 256;
    __syncthreads();
#pragma unroll
    for (int ii = 0; ii < 8; ++ii) {
      const int row = w * 64 + ii * 8 + (lane >> 3);
      gl_lds16((const char*)sh + (size_t)(nb + row) * 128 + sx,
               smA + w * 8192 + ii * 1024);
    }
    s2t[t] = s2g[nb + t];
    ht[t] = hg[nb + t];
    snt[t] = sng[nb + t];
    ir2t[t] = ir2g[nb + t];
    __syncthreads();

    f32x4 acc[4][8];
    {
      short8v bfr[8];
#pragma unroll
      for (int qi = 0; qi < 8; ++qi)
        bfr[qi] = *reinterpret_cast<const short8v*>(smB + ((qi * 16 + l15) << 7) + kx0);
#pragma unroll
      for (int ni = 0; ni < 4; ++ni) {
        const short8v af = *reinterpret_cast<const short8v*>(
            smA + ((w * 64 + ni * 16 + l15) << 7) + kx0);
#pragma unroll
        for (int qi = 0; qi < 8; ++qi)
          acc[ni][qi] = __builtin_amdgcn_mfma_f32_16x16x32_bf16(af, bfr[qi], z4, 0, 0, 0);
      }
#pragma unroll
      for (int qi = 0; qi < 8; ++qi)
        bfr[qi] = *reinterpret_cast<const short8v*>(smB + ((qi * 16 + l15) << 7) + kx1);
#pragma unroll
      for (int ni = 0; ni < 4; ++ni) {
        const short8v af = *reinterpret_cast<const short8v*>(
            smA + ((w * 64 + ni * 16 + l15) << 7) + kx1);
#pragma unroll
        for (int qi = 0; qi < 8; ++qi)
          acc[ni][qi] = __builtin_amdgcn_mfma_f32_16x16x32_bf16(af, bfr[qi], acc[ni][qi], 0, 0, 0);
      }
    }
    // epilogue: C/D map col(q)=lane&15, row(n)=(lane>>4)*4+reg
#pragma unroll
    for (int ni = 0; ni < 4; ++ni) {
#pragma unroll
      for (int r = 0; r < 4; ++r) {
        const int nl = w * 64 + ni * 16 + hi4 + r;
        const float s2n = s2t[nl], hn = ht[nl], snn = snt[nl];
#pragma unroll
        for (int qi = 0; qi < 8; ++qi) {
          const float a = acc[ni][qi][r];
          const float t1 = fmaf(0.5f, s2n, q2h_r[qi]);
          const float thr = fmaf(-qe_r[qi], snn, fmaf(-tau_r[qi], hn, t1));
          if (a >= thr) {
            const int ql = qi * 16 + l15;
            const int n = nb + nl;
            // approx key + rigorous error band (in key units)
            const float ir2v = ir2t[nl];
            const float d2 = 2.0f * (t1 - a);
            const float keyp = (fmaxf(d2, 0.0f) + EPS_SQRT_F) * ir2v;
            const float ev = fmaf(2.0f * qe_r[qi] * snn, ir2v, 1e-5f * keyp) * 1.0002f;
            const unsigned hiw = (bf16_up_pos(keyp + ev) << 16) |
                                 bf16_down_pos(fmaxf(keyp - ev, 0.0f));
            const unsigned long long ce = ((unsigned long long)hiw << 32) | (unsigned)n;
            const int pos = atomicAdd(&cnt128[ql], 1);   // LDS atomic (fast)
            if (pos < slots) {
              cand[((size_t)((qbase + ql) * 64 + chunk)) * slots + pos] = ce;
            } else {
              const int gp = atomicAdd(ovcnt, 1);        // global, ~never
              if (gp < OVCAP) ovf[gp] = ((unsigned)(qbase + ql) << 17) | (unsigned)n;
            }
          }
        }
      }
    }
  }
  __syncthreads();
  if (t < 128) {
    int c = cnt128[t];
    if (c > slots) c = slots;
    ccnt[(size_t)(qbase + t) * 64 + chunk] = c;
  }
}

// ------ final: bracket-prune candidates, exact f32 refine of survivors only
__global__ __launch_bounds__(256) void final_kernel(
    const unsigned long long* __restrict__ cand, const int* __restrict__ ccnt,
    const int* __restrict__ ovcnt, const unsigned int* __restrict__ ovf,
    const float* __restrict__ qGr, const float* __restrict__ q2g,
    const float* __restrict__ stored, const float* __restrict__ s2g,
    const float* __restrict__ ir2g, float* __restrict__ out, int slots) {
  __shared__ __align__(16) float qgl[64];
  __shared__ int ccl[64];
  __shared__ int offs[64];
  __shared__ unsigned short cid[MCAP];
  __shared__ int mtot;
  __shared__ int scnt;
  __shared__ unsigned int sidx[SCAP];
  __shared__ float wk[4][16];
  __shared__ int wi[4][16];
  __shared__ float u16s;
  const int t = threadIdx.x;
  const int lane = t & 63, w = t >> 6;
  const int q = blockIdx.x;
  if (t < 64) {
    qgl[t] = qGr[(size_t)q * DCC + t];
    ccl[t] = min(ccnt[(size_t)q * 64 + t], slots);
  }
  if (t == 0) scnt = 0;
  __syncthreads();
  if (w == 0) {  // exclusive prefix over 64 counts (shfl scan)
    int c = ccl[lane];
    int inc = c;
#pragma unroll
    for (int off = 1; off < 64; off <<= 1) {
      const int u = __shfl_up(inc, off);
      if (lane >= off) inc += u;
    }
    offs[lane] = inc - c;
    if (lane == 63) mtot = inc;
  }
  __syncthreads();
  const int m = mtot;  // m <= 64*slots <= MCAP always
  if (t < 64) {
    const int base = offs[t], c = ccl[t];
    for (int j = 0; j < c; ++j) cid[base + j] = (unsigned short)t;
  }
  __syncthreads();
  const float q2v = q2g[q];
  float k16[16];
  int i16[16];
  // ---- pass A: U16 = 16th smallest upper bound (streamed, no gathers)
#pragma unroll
  for (int s = 0; s < 16; ++s) { k16[s] = 3.0e38f; i16[s] = 0x7FFFFFFF; }
  for (int i = t; i < m; i += 256) {
    const int k = cid[i];
    const int j = i - offs[k];
    const unsigned long long ce = cand[((size_t)(q * 64 + k)) * slots + j];
    const float upF = __uint_as_float((unsigned)(ce >> 32) & 0xFFFF0000u);
    ins16(upF, i, k16, i16);
  }
  wave_extract16(k16, i16, lane, &wk[w][0], &wi[w][0]);
  __syncthreads();
  if (w == 0) {
    float v = wk[lane >> 4][lane & 15];
    float mv16 = 3.0e38f;
    for (int r = 0; r < K_TOP; ++r) {
      float mv = v;
      int who = lane;
#pragma unroll
      for (int off = 32; off; off >>= 1) {
        const float ov = __shfl_xor(mv, off);
        const int ow = __shfl_xor(who, off);
        if (ov < mv || (ov == mv && ow < who)) { mv = ov; who = ow; }
      }
      mv16 = mv;
      if (lane == who) v = 3.0e38f;
    }
    if (lane == 0) u16s = mv16;
  }
  __syncthreads();
  const float U16 = u16s;
  // ---- pass B: survivors = { lower <= U16 }  (provable superset of top-16)
  for (int i = t; i < m; i += 256) {
    const int k = cid[i];
    const int j = i - offs[k];
    const unsigned long long ce = cand[((size_t)(q * 64 + k)) * slots + j];
    const float loF = __uint_as_float((unsigned)(ce >> 32) << 16);
    if (loF <= U16) {
      const int pos = atomicAdd(&scnt, 1);
      if (pos < SCAP) sidx[pos] = (unsigned)ce;
    }
  }
  __syncthreads();
  const int sc = scnt;
  // ---- exact phase
#pragma unroll
  for (int s = 0; s < 16; ++s) { k16[s] = 3.0e38f; i16[s] = 0x7FFFFFFF; }
  if (sc <= SCAP) {
    for (int i = t; i < sc; i += 256) {
      const int n = (int)sidx[i];
      ins16(exact_key(stored, qgl, q2v, s2g, ir2g, n), n, k16, i16);
    }
  } else {  // survivor overflow (astronomically rare): refine everything
    for (int i = t; i < m; i += 256) {
      const int k = cid[i];
      const int j = i - offs[k];
      const int n = (int)(unsigned)cand[((size_t)(q * 64 + k)) * slots + j];
      ins16(exact_key(stored, qgl, q2v, s2g, ir2g, n), n, k16, i16);
    }
  }
  {  // global overflow list (normally empty): always refined exactly
    int oc = *ovcnt;
    if (oc > OVCAP) oc = OVCAP;
    for (int i = t; i < oc; i += 256) {
      const unsigned pk = ovf[i];
      if ((int)(pk >> 17) == q) {
        const int n = (int)(pk & 0x1FFFFu);
        ins16(exact_key(stored, qgl, q2v, s2g, ir2g, n), n, k16, i16);
      }
    }
  }
  __syncthreads();  // wk/wi reuse
  wave_extract16(k16, i16, lane, &wk[w][0], &wi[w][0]);
  __syncthreads();
  if (w == 0) {  // cross-wave lexicographic merge of 4x16 entries
    float v = wk[lane >> 4][lane & 15];
    int id = wi[lane >> 4][lane & 15];
    for (int r = 0; r < K_TOP; ++r) {
      float mv = v;
      int mid = id;
      int who = lane;
#pragma unroll
      for (int off = 32; off; off >>= 1) {
        const float ov = __shfl_xor(mv, off);
        const int oid = __shfl_xor(mid, off);
        const int ow = __shfl_xor(who, off);
        if (ov < mv || (ov == mv && oid < mid)) { mv = ov; mid = oid; who = ow; }
      }
      if (lane == 0) {
        out[q * K_TOP + r] = sqrtf(mv);
        out[NQ * K_TOP + q * K_TOP + r] = (float)mid;
      }
      if (lane == who) { v = 3.0e38f; id = 0x7FFFFFFF; }
    }
  }
}

// ----------------------------------------------------------------- launcher
extern "C" void kernel_launch(void* const* d_in, const int* in_sizes, int n_in,
                              void* d_out, int out_size, void* d_ws, size_t ws_size,
                              hipStream_t stream) {
  const float* query  = (const float*)d_in[0];
  const float* stored = (const float*)d_in[1];
  const float* resil  = (const float*)d_in[2];
  const float* W      = (const float*)d_in[3];
  const float* M      = (const float*)d_in[4];

  char* ws = (char*)d_ws;
  size_t off = 0;
  float* G    = (float*)(ws + off); off += 16384;
  float* qGT  = (float*)(ws + off); off += 262144;   // [64][1024] f32
  float* qGr  = (float*)(ws + off); off += 262144;   // [1024][64] f32
  unsigned short* qGh = (unsigned short*)(ws + off); off += 131072;  // bf16
  float* q2   = (float*)(ws + off); off += 4096;
  float* qe   = (float*)(ws + off); off += 4096;
  float* tau  = (float*)(ws + off); off += 4096;
  float* s2   = (float*)(ws + off); off += 524288;
  float* h    = (float*)(ws + off); off += 524288;
  float* sn   = (float*)(ws + off); off += 524288;
  float* ir2  = (float*)(ws + off); off += 524288;
  int*   ccnt = (int*)(ws + off);   off += 262144;   // [1024][64]
  int*   ovcnt = (int*)(ws + off);  off += 4096;
  unsigned int* ovf = (unsigned int*)(ws + off); off += 262144;  // 65536 entries
  unsigned short* sh = (unsigned short*)(ws + off); off += 16777216;  // bf16 rows
  unsigned long long* cand = (unsigned long long*)(ws + off);  // [1024][64][slots] u64
  float* skeys = (float*)cand;  // overlay (8 MB, used before cand)

  int slots = 44;
  if (ws_size < off + (size_t)NQ * 64 * 44 * 8) slots = 32;
  if (ws_size < off + (size_t)NQ * 64 * 32 * 8) slots = 22;

  float* out = (float*)d_out;

  hipMemsetAsync(ovcnt, 0, 4096, stream);
  g_kernel<<<16, 256, 0, stream>>>(M, G);
  q_kernel<<<NQ / 4, 256, 0, stream>>>(query, W, G, qGT, qGr, qGh, q2, qe);
  s_kernel<<<NS / 64, 256, 0, stream>>>(stored, resil, G, s2, sn, ir2, h, sh);
  sub_kernel<<<dim3(32, 8), 256, 0, stream>>>(stored, qGT, q2, s2, ir2, skeys);
  tau_select<<<NQ, 256, 0, stream>>>(skeys, tau);
  main_mfma<<<dim3(64, 8), 256, 0, stream>>>(sh, qGh, q2, qe, tau, s2, h, sn, ir2,
                                             ccnt, ovcnt, ovf, cand, slots);
  final_kernel<<<NQ, 256, 0, stream>>>(cand, ccnt, ovcnt, ovf, qGr, q2,
                                       stored, s2, ir2, out, slots);
}

// Round 6
// 257.438 us; speedup vs baseline: 2.1128x; 1.1786x over previous
//
#include <hip/hip_runtime.h>
#include <stdint.h>

// Problem constants (fixed by the reference)
#define NQ 1024
#define NS 131072
#define DMM 2048
#define DCC 64
#define K_TOP 16
#define EPS_RES_F 1e-8f
#define EPS_SQRT_F 1e-12f
#define EPS_A 0.01f       // bf16 hi-only dot abs-error coeff (rigorous bound ~0.004)

#define NCH 128           // candidate chunks over N
#define CHR (NS / NCH)    // 1024 rows per chunk
#define OVCAP 65536       // global overflow list capacity (normally ~empty)
#define SLOTS_MAX 24
#define MCAP (NCH * SLOTS_MAX)  // 3072
#define SCAP 1024         // survivor capacity (expected ~30)

typedef __attribute__((ext_vector_type(8))) short short8v;  // 8 x bf16
typedef __attribute__((ext_vector_type(4))) float f32x4;

__device__ __forceinline__ unsigned short f2bf(float x) {  // RNE f32->bf16
  unsigned u = __float_as_uint(x);
  unsigned r = (u + 0x7FFFu + ((u >> 16) & 1u)) >> 16;
  return (unsigned short)r;
}
// directed bf16 rounding for POSITIVE floats (bounds stay provable)
__device__ __forceinline__ unsigned bf16_down_pos(float x) {
  return __float_as_uint(x) >> 16;
}
__device__ __forceinline__ unsigned bf16_up_pos(float x) {
  const unsigned u = __float_as_uint(x);
  return (u >> 16) + ((u & 0xFFFFu) ? 1u : 0u);
}

__device__ __forceinline__ void gl_lds16(const void* g, void* l) {
  __builtin_amdgcn_global_load_lds(
      (const __attribute__((address_space(1))) unsigned int*)g,
      (__attribute__((address_space(3))) unsigned int*)l, 16, 0, 0);
}

__device__ __forceinline__ bool lex_lt(float ka, int ia, float kb, int ib) {
  return (ka < kb) || (ka == kb && ia < ib);
}

__device__ __forceinline__ void ins16(float key, int idx, float (&k16)[16], int (&i16)[16]) {
  if (lex_lt(key, idx, k16[15], i16[15])) {
#pragma unroll
    for (int s = 15; s >= 1; --s) {
      const bool dprev = lex_lt(key, idx, k16[s - 1], i16[s - 1]);
      const bool dcur = lex_lt(key, idx, k16[s], i16[s]);
      const float nk = dprev ? k16[s - 1] : key;
      const int ni = dprev ? i16[s - 1] : idx;
      if (dcur) { k16[s] = nk; i16[s] = ni; }
    }
    if (lex_lt(key, idx, k16[0], i16[0])) { k16[0] = key; i16[0] = idx; }
  }
}

// exact key chain — MUST stay bit-identical to sub_kernel's accumulation
__device__ __forceinline__ float exact_key(const float* __restrict__ stored,
                                           const float* qgl, float q2v,
                                           const float4* __restrict__ aux4, int n) {
  const float4* srow = reinterpret_cast<const float4*>(stored + (size_t)n * DCC);
  float a = 0.f;
#pragma unroll
  for (int kb = 0; kb < 16; ++kb) {
    const float4 qv = *reinterpret_cast<const float4*>(&qgl[4 * kb]);
    const float4 sv = srow[kb];
    a = fmaf(qv.w, sv.w, fmaf(qv.z, sv.z, fmaf(qv.y, sv.y, fmaf(qv.x, sv.x, a))));
  }
  const float4 av = aux4[n];
  const float d2 = fmaf(-2.f, a, q2v + av.x);
  return (fmaxf(d2, 0.f) + EPS_SQRT_F) * av.w;
}

// wave-level merge: each lane holds ascending k16/i16; lane0 writes wave top-16
__device__ __forceinline__ void wave_extract16(float (&k16)[16], int (&i16)[16],
                                               int lane, float* ok, int* oi) {
  for (int r = 0; r < K_TOP; ++r) {
    float v = k16[0];
    int id = i16[0];
    int who = lane;
#pragma unroll
    for (int off = 32; off; off >>= 1) {
      const float ov = __shfl_xor(v, off);
      const int oid = __shfl_xor(id, off);
      const int ow = __shfl_xor(who, off);
      if (ov < v || (ov == v && oid < id)) { v = ov; id = oid; who = ow; }
    }
    if (lane == 0) { ok[r] = v; oi[r] = id; }
    if (lane == who) {
#pragma unroll
      for (int s = 0; s < 15; ++s) { k16[s] = k16[s + 1]; i16[s] = i16[s + 1]; }
      k16[15] = 3.0e38f;
      i16[15] = 0x7FFFFFFF;
    }
  }
}

// ---------------------------------------------------------------- G = M M^T
__global__ __launch_bounds__(256) void g_kernel(const float* __restrict__ M,
                                                float* __restrict__ G) {
  __shared__ __align__(16) float Ml[64 * 66];
  const int t = threadIdx.x;
  for (int p = 0; p < 16; ++p) {
    int i = p * 256 + t;
    Ml[(i >> 6) * 66 + (i & 63)] = M[i];
  }
  __syncthreads();
  const int e = blockIdx.x * 256 + t;
  const int i = e >> 6, j = e & 63;
  float a = 0.f;
#pragma unroll
  for (int k = 0; k < 64; ++k) a = fmaf(Ml[i * 66 + k], Ml[j * 66 + k], a);
  G[e] = a;
}

// ---------------- qc = q W ; qG = qc G ; q2 = qc.qG ; qGh bf16 ; qe = eps*|qG|
__global__ __launch_bounds__(256) void q_kernel(
    const float* __restrict__ query, const float* __restrict__ W,
    const float* __restrict__ G, float* __restrict__ qGT,
    float* __restrict__ qGr, unsigned short* __restrict__ qGh,
    float* __restrict__ q2o, float* __restrict__ qeo) {
  __shared__ __align__(16) float qs[4][DMM];
  __shared__ float part[4][4][64];
  __shared__ float qc[4][64];
  const int t = threadIdx.x;
  const int qb = blockIdx.x * 4;
  {
    const float4* src = reinterpret_cast<const float4*>(query + (size_t)qb * DMM);
    float4* dst = reinterpret_cast<float4*>(&qs[0][0]);
#pragma unroll
    for (int r = 0; r < 8; ++r) dst[r * 256 + t] = src[r * 256 + t];
  }
  __syncthreads();
  const int c = t & 63, seg = t >> 6;
  float p0 = 0.f, p1 = 0.f, p2 = 0.f, p3 = 0.f;
  const int kbase = seg * 512;
  for (int ki = 0; ki < 512; ++ki) {
    const int k = kbase + ki;
    const float w = W[(size_t)k * 64 + c];
    p0 = fmaf(qs[0][k], w, p0);
    p1 = fmaf(qs[1][k], w, p1);
    p2 = fmaf(qs[2][k], w, p2);
    p3 = fmaf(qs[3][k], w, p3);
  }
  part[0][seg][c] = p0; part[1][seg][c] = p1;
  part[2][seg][c] = p2; part[3][seg][c] = p3;
  __syncthreads();
  {
    const int q = t >> 6, cc = t & 63;
    qc[q][cc] = part[q][0][cc] + part[q][1][cc] + part[q][2][cc] + part[q][3][cc];
  }
  __syncthreads();
  const int w = t >> 6, lane = t & 63;
  float g = 0.f;
  for (int j = 0; j < 64; ++j) g = fmaf(qc[w][j], G[j * 64 + lane], g);
  const int q = qb + w;
  qGT[(size_t)lane * NQ + q] = g;
  qGr[(size_t)q * DCC + lane] = g;
  qGh[(size_t)q * DCC + lane] = f2bf(g);
  float pr = qc[w][lane] * g;
  float pn = g * g;
#pragma unroll
  for (int off = 32; off; off >>= 1) {
    pr += __shfl_xor(pr, off);
    pn += __shfl_xor(pn, off);
  }
  if (lane == 0) {
    q2o[q] = pr;
    qeo[q] = EPS_A * sqrtf(pn);
  }
}

// ---- aux4[n] = { s2 = s^T G s,  h = (res+eps)^2/2,  sn = |s|,  ir2 = 1/(res+eps)^2 }
// also sh = bf16(stored rows)
__global__ __launch_bounds__(256) void s_kernel(
    const float* __restrict__ stored, const float* __restrict__ resil,
    const float* __restrict__ G, float4* __restrict__ aux4o,
    unsigned short* __restrict__ sho) {
  __shared__ __align__(16) float Gl[64 * 66];
  __shared__ __align__(16) float sst[64 * 64];
  __shared__ float part2[64 * 33];
  __shared__ float ps[64 * 33];
  const int t = threadIdx.x;
  const int nb = blockIdx.x * 64;
  for (int p = 0; p < 16; ++p) {
    int i = p * 256 + t;
    Gl[(i >> 6) * 66 + (i & 63)] = G[i];
  }
  {
    const float4* src = reinterpret_cast<const float4*>(stored + (size_t)nb * DCC);
    float4* dst = reinterpret_cast<float4*>(sst);
#pragma unroll
    for (int r = 0; r < 4; ++r) dst[r * 256 + t] = src[r * 256 + t];
  }
  __syncthreads();
  const int l = t & 31, tw = t >> 5;
  float acc0[8], acc1[8];
#pragma unroll
  for (int i = 0; i < 8; ++i) { acc0[i] = 0.f; acc1[i] = 0.f; }
  for (int kb = 0; kb < 16; ++kb) {
    const float2 ga0 = *reinterpret_cast<const float2*>(&Gl[(4 * kb + 0) * 66 + 2 * l]);
    const float2 ga1 = *reinterpret_cast<const float2*>(&Gl[(4 * kb + 1) * 66 + 2 * l]);
    const float2 ga2 = *reinterpret_cast<const float2*>(&Gl[(4 * kb + 2) * 66 + 2 * l]);
    const float2 ga3 = *reinterpret_cast<const float2*>(&Gl[(4 * kb + 3) * 66 + 2 * l]);
#pragma unroll
    for (int i = 0; i < 8; ++i) {
      const float4 sv = *reinterpret_cast<const float4*>(&sst[(8 * tw + i) * 64 + 4 * kb]);
      acc0[i] = fmaf(ga3.x, sv.w, fmaf(ga2.x, sv.z, fmaf(ga1.x, sv.y, fmaf(ga0.x, sv.x, acc0[i]))));
      acc1[i] = fmaf(ga3.y, sv.w, fmaf(ga2.y, sv.z, fmaf(ga1.y, sv.y, fmaf(ga0.y, sv.x, acc1[i]))));
    }
  }
#pragma unroll
  for (int i = 0; i < 8; ++i) {
    const int n = 8 * tw + i;
    const float2 sj = *reinterpret_cast<const float2*>(&sst[n * 64 + 2 * l]);
    part2[n * 33 + l] = acc0[i] * sj.x + acc1[i] * sj.y;
    ps[n * 33 + l] = sj.x * sj.x + sj.y * sj.y;
  }
  __syncthreads();
  for (int p = 0; p < 16; ++p) {
    const int i = p * 256 + t;
    const int nl = i >> 6, k = i & 63;
    sho[(size_t)(nb + nl) * DCC + k] = f2bf(sst[nl * 64 + k]);
  }
  if (t < 64) {
    float s = 0.f, sp = 0.f;
#pragma unroll
    for (int u = 0; u < 32; ++u) { s += part2[t * 33 + u]; sp += ps[t * 33 + u]; }
    const float rv = resil[nb + t] + EPS_RES_F;
    const float inv = 1.0f / rv;
    aux4o[nb + t] = make_float4(s, 0.5f * rv * rv, sqrtf(sp), inv * inv);
  }
}

// --------- exact f32 keys for the 1/64 subsample (rows n = 64*j, j<2048)
__global__ __launch_bounds__(256) void sub_kernel(
    const float* __restrict__ stored, const float* __restrict__ qGT,
    const float* __restrict__ q2g, const float4* __restrict__ aux4,
    float* __restrict__ skeys) {
  __shared__ __align__(16) float qg[64 * 128];
  __shared__ __align__(16) float sst[64 * 64];
  __shared__ float s2sub[64];
  __shared__ float ir2sub[64];
  const int t = threadIdx.x;
  const int jb = blockIdx.x * 64;
  const int qbase = blockIdx.y * 128;
  for (int p = 0; p < 32; ++p) {
    const int i = p * 256 + t;
    const int k = i >> 7, qq = i & 127;
    qg[k * 128 + qq] = qGT[(size_t)k * NQ + qbase + qq];
  }
#pragma unroll
  for (int p = 0; p < 4; ++p) {
    const int idx = p * 256 + t;
    const int r = idx >> 4, f4 = idx & 15;
    reinterpret_cast<float4*>(sst)[r * 16 + f4] =
        reinterpret_cast<const float4*>(stored + (size_t)(64 * (jb + r)) * DCC)[f4];
  }
  if (t < 64) {
    const float4 v = aux4[64 * (jb + t)];
    s2sub[t] = v.x;
    ir2sub[t] = v.w;
  }
  __syncthreads();
  const int l = t & 31, tw = t >> 5;
  const int q0 = 4 * l;
  float q2r[4];
#pragma unroll
  for (int qq = 0; qq < 4; ++qq) q2r[qq] = q2g[qbase + q0 + qq];
  float acc[4][8];
#pragma unroll
  for (int qq = 0; qq < 4; ++qq)
#pragma unroll
    for (int i = 0; i < 8; ++i) acc[qq][i] = 0.f;
  for (int kb = 0; kb < 16; ++kb) {
    const float4 qa0 = *reinterpret_cast<const float4*>(&qg[(4 * kb + 0) * 128 + q0]);
    const float4 qa1 = *reinterpret_cast<const float4*>(&qg[(4 * kb + 1) * 128 + q0]);
    const float4 qa2 = *reinterpret_cast<const float4*>(&qg[(4 * kb + 2) * 128 + q0]);
    const float4 qa3 = *reinterpret_cast<const float4*>(&qg[(4 * kb + 3) * 128 + q0]);
#pragma unroll
    for (int i = 0; i < 8; ++i) {
      const float4 sv = *reinterpret_cast<const float4*>(&sst[(8 * tw + i) * 64 + 4 * kb]);
      acc[0][i] = fmaf(qa3.x, sv.w, fmaf(qa2.x, sv.z, fmaf(qa1.x, sv.y, fmaf(qa0.x, sv.x, acc[0][i]))));
      acc[1][i] = fmaf(qa3.y, sv.w, fmaf(qa2.y, sv.z, fmaf(qa1.y, sv.y, fmaf(qa0.y, sv.x, acc[1][i]))));
      acc[2][i] = fmaf(qa3.z, sv.w, fmaf(qa2.z, sv.z, fmaf(qa1.z, sv.y, fmaf(qa0.z, sv.x, acc[2][i]))));
      acc[3][i] = fmaf(qa3.w, sv.w, fmaf(qa2.w, sv.z, fmaf(qa1.w, sv.y, fmaf(qa0.w, sv.x, acc[3][i]))));
    }
  }
#pragma unroll
  for (int i = 0; i < 8; ++i) {
    const int jl = 8 * tw + i;
    const float s2v = s2sub[jl];
    const float ir2v = ir2sub[jl];
#pragma unroll
    for (int qq = 0; qq < 4; ++qq) {
      const float d2 = fmaf(-2.f, acc[qq][i], q2r[qq] + s2v);
      const float key = (fmaxf(d2, 0.f) + EPS_SQRT_F) * ir2v;
      skeys[(size_t)(qbase + q0 + qq) * 2048 + jb + jl] = key;
    }
  }
}

// ---- tau[q] = 16th smallest subsample key (exact), *1.0001 margin
__global__ __launch_bounds__(256) void tau_select(
    const float* __restrict__ skeys, float* __restrict__ tau) {
  __shared__ float lk[256 * 17];
  __shared__ float wkv[4][16];
  const int t = threadIdx.x;
  const int lane = t & 63, w = t >> 6;
  const int q = blockIdx.x;
  float k16[16];
#pragma unroll
  for (int s = 0; s < 16; ++s) k16[s] = 3.0e38f;
  for (int i = t; i < 2048; i += 256) {
    const float key = skeys[(size_t)q * 2048 + i];
    if (key < k16[15]) {
#pragma unroll
      for (int s = 15; s >= 1; --s) {
        const bool dprev = key < k16[s - 1];
        const float nk = dprev ? k16[s - 1] : key;
        if (key < k16[s]) k16[s] = nk;
      }
      if (key < k16[0]) k16[0] = key;
    }
  }
#pragma unroll
  for (int s = 0; s < 16; ++s) lk[t * 17 + s] = k16[s];
  __syncthreads();
  {
    int ptr = 0;
    for (int r = 0; r < K_TOP; ++r) {
      float v = lk[t * 17 + ptr];
      int who = lane;
#pragma unroll
      for (int off = 32; off; off >>= 1) {
        const float ov = __shfl_xor(v, off);
        const int ow = __shfl_xor(who, off);
        if (ov < v || (ov == v && ow < who)) { v = ov; who = ow; }
      }
      if (lane == 0) wkv[w][r] = v;
      if (lane == who) ptr++;
    }
  }
  __syncthreads();
  if (w == 0) {
    float v = wkv[lane >> 4][lane & 15];
    float t16 = 0.f;
    for (int r = 0; r < K_TOP; ++r) {
      float mv = v;
      int who = lane;
#pragma unroll
      for (int off = 32; off; off >>= 1) {
        const float ov = __shfl_xor(mv, off);
        const int ow = __shfl_xor(who, off);
        if (ov < mv || (ov == mv && ow < who)) { mv = ov; who = ow; }
      }
      t16 = mv;
      if (lane == who) v = 3.0e38f;
    }
    if (lane == 0) tau[q] = t16 * 1.0001f;
  }
}

// --------------- MFMA screening pass: bf16-hi cross-GEMM + bounded filter
// 128n x 64q block tile; B fragments read directly from L2-resident qGh.
// accept iff  a >= q2/2 + s2/2 - tau*h - (EPS_A*|qG|)*|s|   (provable superset)
// stores u64: [63:48] bf16-UP upper key, [47:32] bf16-DOWN lower key, [31:0] n
__global__ __launch_bounds__(256, 4) void main_mfma(
    const unsigned short* __restrict__ sh, const unsigned short* __restrict__ qGh,
    const float* __restrict__ q2g, const float* __restrict__ qeg,
    const float* __restrict__ taug, const float4* __restrict__ aux4,
    int* __restrict__ ccnt, int* __restrict__ ovcnt,
    unsigned int* __restrict__ ovf, unsigned long long* __restrict__ cand,
    int slots) {
  __shared__ __align__(16) char smA[16384];    // 128 n-rows x 128B, XOR-swizzled
  __shared__ __align__(16) float4 auxl[128];   // per-row {s2,h,sn,ir2}
  __shared__ int cnt64[64];
  const int t = threadIdx.x;
  const int lane = t & 63, w = t >> 6;
  const int l15 = lane & 15, hi4 = (lane >> 4) << 2;
  const int chunk = blockIdx.x;    // 0..127 ; linear%8 == chunk%8 -> XCD pinned
  const int qbase = blockIdx.y * 64;
  const int sx = ((lane & 7) << 4) ^ ((lane >> 3) << 4);
  const int g16 = (lane >> 4) << 4;
  const int swz = (lane & 7) << 4;

  if (t < 64) cnt64[t] = 0;
  float q2h_r[4], tau_r[4], qe_r[4];
#pragma unroll
  for (int qi = 0; qi < 4; ++qi) {
    const int q = qbase + qi * 16 + l15;
    q2h_r[qi] = 0.5f * q2g[q];
    tau_r[qi] = taug[q];
    qe_r[qi] = qeg[q];
  }
  const char* qB = (const char*)qGh;
  const f32x4 z4 = {0.f, 0.f, 0.f, 0.f};

  for (int nt = 0; nt < 8; ++nt) {
    const int nb = chunk * CHR + nt * 128;
    __syncthreads();  // previous tile fully consumed
#pragma unroll
    for (int ii = 0; ii < 4; ++ii) {
      const int row = w * 32 + ii * 8 + (lane >> 3);
      gl_lds16((const char*)sh + (size_t)(nb + row) * 128 + sx,
               smA + w * 4096 + ii * 1024);
    }
    if (t < 128) auxl[t] = aux4[nb + t];
    __syncthreads();  // drains vmcnt (global_load_lds) + lds writes

    f32x4 acc[2][4];
#pragma unroll
    for (int kh = 0; kh < 2; ++kh) {
      short8v bfr[4];
#pragma unroll
      for (int qi = 0; qi < 4; ++qi)
        bfr[qi] = *reinterpret_cast<const short8v*>(
            qB + (((size_t)(qbase + qi * 16 + l15)) << 7) + (kh << 6) + g16);
      const int kx = ((kh << 6) | g16) ^ swz;
#pragma unroll
      for (int ni = 0; ni < 2; ++ni) {
        const short8v af = *reinterpret_cast<const short8v*>(
            smA + ((w * 32 + ni * 16 + l15) << 7) + kx);
#pragma unroll
        for (int qi = 0; qi < 4; ++qi)
          acc[ni][qi] = (kh == 0)
              ? __builtin_amdgcn_mfma_f32_16x16x32_bf16(af, bfr[qi], z4, 0, 0, 0)
              : __builtin_amdgcn_mfma_f32_16x16x32_bf16(af, bfr[qi], acc[ni][qi], 0, 0, 0);
      }
    }
    // epilogue: C/D map col(q)=lane&15, row(n)=(lane>>4)*4+reg
#pragma unroll
    for (int ni = 0; ni < 2; ++ni) {
#pragma unroll
      for (int r = 0; r < 4; ++r) {
        const int nl = w * 32 + ni * 16 + hi4 + r;
        const float4 av = auxl[nl];  // {s2, h, sn, ir2}
#pragma unroll
        for (int qi = 0; qi < 4; ++qi) {
          const float a = acc[ni][qi][r];
          const float t1 = fmaf(0.5f, av.x, q2h_r[qi]);
          const float thr = fmaf(-qe_r[qi], av.z, fmaf(-tau_r[qi], av.y, t1));
          if (a >= thr) {
            const int ql = qi * 16 + l15;
            const int n = nb + nl;
            const float d2 = 2.0f * (t1 - a);
            const float keyp = (fmaxf(d2, 0.0f) + EPS_SQRT_F) * av.w;
            const float ev = fmaf(2.0f * qe_r[qi] * av.z, av.w, 1e-5f * keyp) * 1.0002f;
            const unsigned hiw = (bf16_up_pos(keyp + ev) << 16) |
                                 bf16_down_pos(fmaxf(keyp - ev, 0.0f));
            const unsigned long long ce = ((unsigned long long)hiw << 32) | (unsigned)n;
            const int pos = atomicAdd(&cnt64[ql], 1);   // LDS atomic (fast)
            if (pos < slots) {
              cand[((size_t)((qbase + ql) * NCH + chunk)) * slots + pos] = ce;
            } else {
              const int gp = atomicAdd(ovcnt, 1);        // global, ~never
              if (gp < OVCAP) ovf[gp] = ((unsigned)(qbase + ql) << 17) | (unsigned)n;
            }
          }
        }
      }
    }
  }
  __syncthreads();
  if (t < 64) {
    int c = cnt64[t];
    if (c > slots) c = slots;
    ccnt[(size_t)(qbase + t) * NCH + chunk] = c;
  }
}

// ------ final: bracket-prune candidates, exact f32 refine of survivors only
__global__ __launch_bounds__(256) void final_kernel(
    const unsigned long long* __restrict__ cand, const int* __restrict__ ccnt,
    const int* __restrict__ ovcnt, const unsigned int* __restrict__ ovf,
    const float* __restrict__ qGr, const float* __restrict__ q2g,
    const float* __restrict__ stored, const float4* __restrict__ aux4,
    float* __restrict__ out, int slots) {
  __shared__ __align__(16) float qgl[64];
  __shared__ int ccl[NCH];
  __shared__ int offs[NCH];
  __shared__ int sc[NCH];
  __shared__ unsigned short cid[MCAP];
  __shared__ int mtot;
  __shared__ int scnt;
  __shared__ unsigned int sidx[SCAP];
  __shared__ float wk[4][16];
  __shared__ int wi[4][16];
  __shared__ float u16s;
  const int t = threadIdx.x;
  const int lane = t & 63, w = t >> 6;
  const int q = blockIdx.x;
  if (t < 64) qgl[t] = qGr[(size_t)q * DCC + t];
  if (t < NCH) {
    const int c = min(ccnt[(size_t)q * NCH + t], slots);
    ccl[t] = c;
    sc[t] = c;
  }
  if (t == 0) scnt = 0;
  __syncthreads();
  // Hillis-Steele inclusive scan over NCH=128 counts
  for (int d = 1; d < NCH; d <<= 1) {
    int v = 0;
    if (t < NCH && t >= d) v = sc[t - d];
    __syncthreads();
    if (t < NCH && t >= d) sc[t] += v;
    __syncthreads();
  }
  if (t < NCH) offs[t] = sc[t] - ccl[t];
  if (t == NCH - 1) mtot = sc[NCH - 1];
  __syncthreads();
  const int m = mtot;  // m <= NCH*slots <= MCAP always
  if (t < NCH) {
    const int base = offs[t], c = ccl[t];
    for (int j = 0; j < c; ++j) cid[base + j] = (unsigned short)t;
  }
  __syncthreads();
  const float q2v = q2g[q];
  float k16[16];
  int i16[16];
  // ---- pass A: U16 = 16th smallest upper bound (streamed, no gathers)
#pragma unroll
  for (int s = 0; s < 16; ++s) { k16[s] = 3.0e38f; i16[s] = 0x7FFFFFFF; }
  for (int i = t; i < m; i += 256) {
    const int k = cid[i];
    const int j = i - offs[k];
    const unsigned long long ce = cand[((size_t)(q * NCH + k)) * slots + j];
    const float upF = __uint_as_float((unsigned)(ce >> 32) & 0xFFFF0000u);
    ins16(upF, i, k16, i16);
  }
  wave_extract16(k16, i16, lane, &wk[w][0], &wi[w][0]);
  __syncthreads();
  if (w == 0) {
    float v = wk[lane >> 4][lane & 15];
    float mv16 = 3.0e38f;
    for (int r = 0; r < K_TOP; ++r) {
      float mv = v;
      int who = lane;
#pragma unroll
      for (int off = 32; off; off >>= 1) {
        const float ov = __shfl_xor(mv, off);
        const int ow = __shfl_xor(who, off);
        if (ov < mv || (ov == mv && ow < who)) { mv = ov; who = ow; }
      }
      mv16 = mv;
      if (lane == who) v = 3.0e38f;
    }
    if (lane == 0) u16s = mv16;
  }
  __syncthreads();
  const float U16 = u16s;
  // ---- pass B: survivors = { lower <= U16 }  (provable superset of top-16)
  for (int i = t; i < m; i += 256) {
    const int k = cid[i];
    const int j = i - offs[k];
    const unsigned long long ce = cand[((size_t)(q * NCH + k)) * slots + j];
    const float loF = __uint_as_float((unsigned)(ce >> 32) << 16);
    if (loF <= U16) {
      const int pos = atomicAdd(&scnt, 1);
      if (pos < SCAP) sidx[pos] = (unsigned)ce;
    }
  }
  __syncthreads();
  const int sc2 = scnt;
  // ---- exact phase
#pragma unroll
  for (int s = 0; s < 16; ++s) { k16[s] = 3.0e38f; i16[s] = 0x7FFFFFFF; }
  if (sc2 <= SCAP) {
    for (int i = t; i < sc2; i += 256) {
      const int n = (int)sidx[i];
      ins16(exact_key(stored, qgl, q2v, aux4, n), n, k16, i16);
    }
  } else {  // survivor overflow (astronomically rare): refine everything
    for (int i = t; i < m; i += 256) {
      const int k = cid[i];
      const int j = i - offs[k];
      const int n = (int)(unsigned)cand[((size_t)(q * NCH + k)) * slots + j];
      ins16(exact_key(stored, qgl, q2v, aux4, n), n, k16, i16);
    }
  }
  {  // global overflow list (normally empty): always refined exactly
    int oc = *ovcnt;
    if (oc > OVCAP) oc = OVCAP;
    for (int i = t; i < oc; i += 256) {
      const unsigned pk = ovf[i];
      if ((int)(pk >> 17) == q) {
        const int n = (int)(pk & 0x1FFFFu);
        ins16(exact_key(stored, qgl, q2v, aux4, n), n, k16, i16);
      }
    }
  }
  __syncthreads();  // wk/wi reuse
  wave_extract16(k16, i16, lane, &wk[w][0], &wi[w][0]);
  __syncthreads();
  if (w == 0) {  // cross-wave lexicographic merge of 4x16 entries
    float v = wk[lane >> 4][lane & 15];
    int id = wi[lane >> 4][lane & 15];
    for (int r = 0; r < K_TOP; ++r) {
      float mv = v;
      int mid = id;
      int who = lane;
#pragma unroll
      for (int off = 32; off; off >>= 1) {
        const float ov = __shfl_xor(mv, off);
        const int oid = __shfl_xor(mid, off);
        const int ow = __shfl_xor(who, off);
        if (ov < mv || (ov == mv && oid < mid)) { mv = ov; mid = oid; who = ow; }
      }
      if (lane == 0) {
        out[q * K_TOP + r] = sqrtf(mv);
        out[NQ * K_TOP + q * K_TOP + r] = (float)mid;
      }
      if (lane == who) { v = 3.0e38f; id = 0x7FFFFFFF; }
    }
  }
}

// ----------------------------------------------------------------- launcher
extern "C" void kernel_launch(void* const* d_in, const int* in_sizes, int n_in,
                              void* d_out, int out_size, void* d_ws, size_t ws_size,
                              hipStream_t stream) {
  const float* query  = (const float*)d_in[0];
  const float* stored = (const float*)d_in[1];
  const float* resil  = (const float*)d_in[2];
  const float* W      = (const float*)d_in[3];
  const float* M      = (const float*)d_in[4];

  char* ws = (char*)d_ws;
  size_t off = 0;
  float* G    = (float*)(ws + off); off += 16384;
  float* qGT  = (float*)(ws + off); off += 262144;   // [64][1024] f32
  float* qGr  = (float*)(ws + off); off += 262144;   // [1024][64] f32
  unsigned short* qGh = (unsigned short*)(ws + off); off += 131072;  // bf16
  float* q2   = (float*)(ws + off); off += 4096;
  float* qe   = (float*)(ws + off); off += 4096;
  float* tau  = (float*)(ws + off); off += 4096;
  float4* aux4 = (float4*)(ws + off); off += (size_t)NS * 16;  // 2 MB
  int*   ccnt = (int*)(ws + off);   off += (size_t)NQ * NCH * 4;  // 512 KB
  int*   ovcnt = (int*)(ws + off);  off += 4096;
  unsigned int* ovf = (unsigned int*)(ws + off); off += OVCAP * 4;  // 256 KB
  unsigned short* sh = (unsigned short*)(ws + off); off += 16777216;  // bf16 rows
  unsigned long long* cand = (unsigned long long*)(ws + off);  // [NQ][NCH][slots]
  float* skeys = (float*)cand;  // overlay (8 MB, used before cand)

  int slots = SLOTS_MAX;  // 24
  if (ws_size < off + (size_t)NQ * NCH * 24 * 8) slots = 16;
  if (ws_size < off + (size_t)NQ * NCH * 16 * 8) slots = 12;

  float* out = (float*)d_out;

  hipMemsetAsync(ovcnt, 0, 4096, stream);
  g_kernel<<<16, 256, 0, stream>>>(M, G);
  q_kernel<<<NQ / 4, 256, 0, stream>>>(query, W, G, qGT, qGr, qGh, q2, qe);
  s_kernel<<<NS / 64, 256, 0, stream>>>(stored, resil, G, aux4, sh);
  sub_kernel<<<dim3(32, 8), 256, 0, stream>>>(stored, qGT, q2, aux4, skeys);
  tau_select<<<NQ, 256, 0, stream>>>(skeys, tau);
  main_mfma<<<dim3(NCH, NQ / 64), 256, 0, stream>>>(sh, qGh, q2, qe, tau, aux4,
                                                    ccnt, ovcnt, ovf, cand, slots);
  final_kernel<<<NQ, 256, 0, stream>>>(cand, ccnt, ovcnt, ovf, qGr, q2,
                                       stored, aux4, out, slots);
}